// Round 3
// 480.646 us; speedup vs baseline: 1.3992x; 1.3992x over previous
//
#include <hip/hip_runtime.h>
#include <stdint.h>

// ---------------------------------------------------------------------------
// MultiMonotoneHollowConv, round 4 (attempt 3; broker outage suspected): MFMA Y1.
//   out0 = -( G00(5x5,center->-G10c[phase]) * x0  +  T10^T(Y1)  - b0^*g0 )
//   out1 = -( W11^T(3x3) * Y1  -  sub1_blockdiag * x1  - b1^*g1 )
//   Y1   = conv(x0,W10,s2,p3) + conv(x1,W11,s1,p2)   [MFMA bf16,
//          weights split hi+lo bf16 so only x carries bf16 rounding]
// MFMA frag layouts (gfx950, HW-verified per guide):
//   A[m=lane&15][k=quad*8+j], B[k=quad*8+j][n=lane&15], D: row m=quad*4+reg,
//   col n=lane&15.  K-chunks use ch-octet LDS planes so each B-frag is one
//   conflict-free ds_read_b128.
// ---------------------------------------------------------------------------

using short8 = __attribute__((ext_vector_type(8))) short;
using f32x4  = __attribute__((ext_vector_type(4))) float;

#define B_ 16

// workspace byte offsets (total ~34.45 MB; must stay < ~35.1 MB proven safe)
static constexpr size_t Y1T_OFF  = 0;                        // [16][130][132][32] bf16
static constexpr size_t Y1T_ROWB = 132 * 64;                 // 8448 B per (b,iy) row
static constexpr size_t X1T_OFF  = (size_t)16 * 130 * 132 * 64;        // 17,571,840
static constexpr size_t AB0_OFF  = X1T_OFF + (size_t)16 * 128 * 128 * 64; // +16,777,216
static constexpr size_t AB1_OFF  = AB0_OFF + 24 * 1024;     // blob0: 24 chunks
static constexpr size_t SUM_OFF  = AB1_OFF + 20 * 1024;     // blob1: 10 chunks x 2
static constexpr size_t AB2_OFF  = SUM_OFF + 1024;          // y1 fwd weights: 56 chunks

__device__ __forceinline__ uint32_t bf16rne(float v) {
  uint32_t u = __float_as_uint(v);
  return (u + 0x7fffu + ((u >> 16) & 1u)) >> 16;
}
__device__ __forceinline__ uint32_t packbf(float lo, float hi) {
  return bf16rne(lo) | (bf16rne(hi) << 16);
}
__device__ __forceinline__ f32x4 mfma16(short8 a, short8 b, f32x4 c) {
  return __builtin_amdgcn_mfma_f32_16x16x32_bf16(a, b, c, 0, 0, 0);
}

// ---------------------------------------------------------------------------
// Weight blobs in exact A-fragment order (bf16), plus zero the norm sums.
// blob0 (out0): [0..12] G00 tap-pairs (k=tap_sub*16+ch), center tap zeroed;
//               [13..21] W10t taps (k=o);  [22,23] -G10c parity chunks (py=0,1;
//               k<16 even-px rows, k>=16 odd-px rows).
// blob1 (out1): [t=0..8][h=0,1] W11 taps (k=o, m=h*16+..); [9][h] -sub1 blockdiag.
// blob2 (y1 fwd): [t 0..8][h][part hi/lo] W11 fwd (k=in ch, m=out ch h*16+..)
//                 then [c5 0..4][h][part] W10 fwd tap-pairs (k=qh*16+ich,
//                 tap = 2*c5+qh, tap 9 zero-padded).
__global__ void blob_k(const float* __restrict__ W00, const float* __restrict__ W10,
                       const float* __restrict__ W11, char* __restrict__ ws) {
  int e = blockIdx.x * 256 + threadIdx.x;
  if (e < 2) ((float*)(ws + SUM_OFF))[e] = 0.f;
  if (e < 12288) {
    int chunk = e >> 9, le = e & 511, lane = le >> 3, j = le & 7;
    int q = lane >> 4, m = lane & 15;
    float val = 0.f;
    if (chunk < 13) {
      int t = 2 * chunk + (q >> 1);
      int n = ((q & 1) << 3) + j;
      if (t <= 24 && t != 12) {
        int dy = t / 5 - 2, dx = t % 5 - 2;
        for (int o = 0; o < 16; ++o) {
          const float* wm = W00 + (o * 16 + m) * 9;
          const float* wn = W00 + (o * 16 + n) * 9;
          for (int ay = 0; ay < 3; ++ay) {
            int ay2 = ay + dy; if ((unsigned)ay2 > 2u) continue;
            for (int ax = 0; ax < 3; ++ax) {
              int ax2 = ax + dx; if ((unsigned)ax2 > 2u) continue;
              val += wm[ay * 3 + ax] * wn[ay2 * 3 + ax2];
            }
          }
        }
      }
    } else if (chunk < 22) {
      int tap = chunk - 13;
      int o = ((lane >> 4) << 3) + j;      // k = q*8+j
      val = W10[(o * 16 + m) * 9 + tap];
    } else {
      int py = chunk - 22;
      int k = ((lane >> 4) << 3) + j;
      int par = k >> 4, n = k & 15;
      for (int o = 0; o < 32; ++o) {
        const float* wn = W10 + (o * 16 + n) * 9;
        const float* wm = W10 + (o * 16 + m) * 9;
        for (int by = 0; by < 3; ++by) {
          if ((py == 0) ? (by != 1) : (by == 1)) continue;
          for (int bx = 0; bx < 3; ++bx) {
            if ((par == 0) ? (bx != 1) : (bx == 1)) continue;
            val -= wn[by * 3 + bx] * wm[by * 3 + bx];
          }
        }
      }
    }
    ((uint16_t*)(ws + AB0_OFF))[chunk * 512 + lane * 8 + j] = (uint16_t)bf16rne(val);
  } else if (e < 12288 + 10240) {
    int e2 = e - 12288;
    int chunk = e2 >> 10, r = e2 & 1023, h = r >> 9, le = r & 511;
    int lane = le >> 3, j = le & 7;
    int m = h * 16 + (lane & 15);
    int kk = ((lane >> 4) << 3) + j;      // k = q*8+j
    float val = 0.f;
    if (chunk < 9) {
      val = W11[(kk * 32 + m) * 9 + chunk];      // o = kk, tap = chunk
    } else if ((kk >> 4) == h) {
      int np = kk & 15;
      float s = 0.f;
      for (int o = 0; o < 32; ++o)
        for (int t = 0; t < 9; ++t)
          s += W11[(o * 32 + m) * 9 + t] * W11[(o * 32 + h * 16 + np) * 9 + t];
      val = -s;
    }
    ((uint16_t*)(ws + AB1_OFF))[(chunk * 2 + h) * 512 + lane * 8 + j] = (uint16_t)bf16rne(val);
  } else if (e < 12288 + 10240 + 28672) {
    int e3 = e - 22528;
    int chunk = e3 >> 9, le = e3 & 511;
    int lane = le >> 3, j = le & 7;
    int q = lane >> 4, m = lane & 15;
    int k = q * 8 + j;
    int part;
    float val = 0.f;
    if (chunk < 36) {
      int t = chunk >> 2, h = (chunk >> 1) & 1;
      part = chunk & 1;
      int o = h * 16 + m;
      val = W11[(o * 32 + k) * 9 + t];           // fwd: A[m=o][k=ich]
    } else {
      int c2 = chunk - 36;
      int c5 = c2 >> 2, h = (c2 >> 1) & 1;
      part = c2 & 1;
      int tap = 2 * c5 + (k >> 4);
      int o = h * 16 + m;
      if (tap <= 8) val = W10[(o * 16 + (k & 15)) * 9 + tap];
    }
    uint32_t hi = bf16rne(val);
    uint16_t outv;
    if (part == 0) outv = (uint16_t)hi;
    else outv = (uint16_t)bf16rne(val - __uint_as_float(hi << 16));
    ((uint16_t*)(ws + AB2_OFF))[chunk * 512 + lane * 8 + j] = outv;
  }
}

// ---------------------------------------------------------------------------
__global__ void sumsq_k(const float* __restrict__ src, int n, float* __restrict__ dst) {
  float s = 0.f;
  for (int i = blockIdx.x * blockDim.x + threadIdx.x; i < n; i += gridDim.x * blockDim.x) {
    float v = src[i];
    s += v * v;
  }
  #pragma unroll
  for (int off = 32; off > 0; off >>= 1) s += __shfl_down(s, off, 64);
  if ((threadIdx.x & 63) == 0) atomicAdd(dst, s);
}

// ---------------------------------------------------------------------------
// x1t[b][r][c][ch] = bf16(x1[b][ch][r][c])
__global__ __launch_bounds__(256) void x1t_k(const float* __restrict__ x1, char* __restrict__ ws) {
  __shared__ __align__(16) uint16_t tmp[128 * 32];
  int b = blockIdx.x >> 7, r = blockIdx.x & 127;
  int tid = threadIdx.x;
  for (int e = tid; e < 4096; e += 256) {
    int ch = e >> 7, c = e & 127;
    float v = x1[((size_t)(b * 32 + ch) * 128 + r) * 128 + c];
    tmp[c * 32 + ch] = (uint16_t)bf16rne(v);
  }
  __syncthreads();
  char* dst = ws + X1T_OFF + ((size_t)(b * 128 + r) * 128) * 64;
  for (int e = tid; e < 512; e += 256)
    *(short8*)(dst + e * 16) = *(const short8*)((const char*)tmp + e * 16);
}

// ---------------------------------------------------------------------------
// Y1 via MFMA: one block per (b, iy); 4 waves; 9 px-frags of 16 (130 used).
// LDS x0s: [ql 2][row 3][par 2][half-col 146][ch8] bf16 (col = 2h+p-3),
//          so stride-2 taps become unit-stride ds_read_b128.
// LDS x1s: [q 4][row 3][col 148][ch8] bf16 (col cs <-> x1 col cs-2).
// Weights from AB2 blob: hi+lo bf16 pairs -> only x carries bf16 rounding.
__global__ __launch_bounds__(256) void y1m_k(const float* __restrict__ x0,
                                             char* __restrict__ ws) {
  __shared__ __align__(16) uint16_t x0s[2 * 3 * 2 * 146 * 8];   // 28,032 B
  __shared__ __align__(16) uint16_t x1s[4 * 3 * 148 * 8];       // 28,416 B
  int tid = threadIdx.x;
  int b = blockIdx.x / 130, iy = blockIdx.x % 130;

  { // zero-fill both tiles (covers all pads / OOB rows)
    uint4 z = make_uint4(0u, 0u, 0u, 0u);
    for (int e = tid; e < 1752; e += 256) ((uint4*)x0s)[e] = z;
    for (int e = tid; e < 1776; e += 256) ((uint4*)x1s)[e] = z;
  }
  __syncthreads();

  { // stage x0 rows 2iy-3..2iy-1 (fp32 -> bf16, even/odd col split)
    const float* x0b = x0 + (size_t)b * 1048576;
    for (int e = tid; e < 6144; e += 256) {
      int r = e >> 11;            // 0..2
      int ch0 = ((e >> 8) & 7) * 2;
      int c = e & 255;
      int gy = 2 * iy + r - 3;
      float v0 = 0.f, v1 = 0.f;
      if ((unsigned)gy < 256u) {
        const float* rp = x0b + (size_t)ch0 * 65536 + (size_t)gy * 256 + c;
        v0 = rp[0]; v1 = rp[65536];
      }
      int sc = c + 3, p = sc & 1, hc = sc >> 1;
      *(uint32_t*)((char*)x0s + ((((ch0 >> 3) * 3 + r) * 2 + p) * 146 + hc) * 16 + (ch0 & 7) * 2)
          = packbf(v0, v1);
    }
  }
  { // stage x1 rows iy-2..iy (bf16 copy from x1t, shifted +2 cols)
    const char* x1tb = ws + X1T_OFF;
    for (int e = tid; e < 1536; e += 256) {
      int row = e >> 9, rr = e & 511, c = rr >> 2, qq = rr & 3;
      int gy = iy + row - 2;
      if ((unsigned)gy < 128u) {
        short8 v = *(const short8*)(x1tb + ((size_t)(b * 128 + gy) * 128 + c) * 64 + qq * 16);
        *(short8*)((char*)x1s + ((qq * 3 + row) * 148 + (c + 2)) * 16) = v;
      }
    }
  }
  __syncthreads();

  int lane = tid & 63, wv = tid >> 6;
  int nn = lane & 15, q = lane >> 4, qh = q >> 1, ql = q & 1;
  const char* ab2 = ws + AB2_OFF;

  f32x4 a00 = {0.f,0.f,0.f,0.f}, a01 = {0.f,0.f,0.f,0.f};
  f32x4 a10 = {0.f,0.f,0.f,0.f}, a11 = {0.f,0.f,0.f,0.f};
  f32x4 a20 = {0.f,0.f,0.f,0.f}, a21 = {0.f,0.f,0.f,0.f};

  // --- W11 fwd (s1,p2): 9 taps, K=32 in-ch ---
  #pragma unroll
  for (int t = 0; t < 9; ++t) {
    const int ay = t / 3, ax = t % 3;
    const char* cb = ab2 + t * 4096 + lane * 16;
    short8 Ah0 = *(const short8*)(cb);
    short8 Al0 = *(const short8*)(cb + 1024);
    short8 Ah1 = *(const short8*)(cb + 2048);
    short8 Al1 = *(const short8*)(cb + 3072);
    const char* bb = (const char*)x1s + ((q * 3 + ay) * 148 + ax + nn) * 16 + wv * 256;
    short8 B0 = *(const short8*)(bb);            // frag wv
    short8 B1 = *(const short8*)(bb + 1024);     // frag wv+4
    a00 = mfma16(Ah0, B0, a00); a00 = mfma16(Al0, B0, a00);
    a01 = mfma16(Ah1, B0, a01); a01 = mfma16(Al1, B0, a01);
    a10 = mfma16(Ah0, B1, a10); a10 = mfma16(Al0, B1, a10);
    a11 = mfma16(Ah1, B1, a11); a11 = mfma16(Al1, B1, a11);
    if (wv == 0) {
      short8 B2 = *(const short8*)(bb + 2048);   // frag 8
      a20 = mfma16(Ah0, B2, a20); a20 = mfma16(Al0, B2, a20);
      a21 = mfma16(Ah1, B2, a21); a21 = mfma16(Al1, B2, a21);
    }
  }

  // --- W10 fwd (s2,p3): tap-pair chunks, k = qh*16 + ich ---
  #pragma unroll
  for (int c5 = 0; c5 < 5; ++c5) {
    const char* cb = ab2 + (36 + c5 * 4) * 1024 + lane * 16;
    short8 Ah0 = *(const short8*)(cb);
    short8 Al0 = *(const short8*)(cb + 1024);
    short8 Ah1 = *(const short8*)(cb + 2048);
    short8 Al1 = *(const short8*)(cb + 3072);
    int tl = 2 * c5 + qh; if (tl > 8) tl = 8;    // tap 9 zero-padded in A
    int by = tl / 3, bx = tl % 3;
    int p = bx & 1, hb = bx >> 1;
    const char* bb = (const char*)x0s + ((((ql * 3 + by) * 2 + p) * 146) + hb + nn) * 16 + wv * 256;
    short8 B0 = *(const short8*)(bb);
    short8 B1 = *(const short8*)(bb + 1024);
    a00 = mfma16(Ah0, B0, a00); a00 = mfma16(Al0, B0, a00);
    a01 = mfma16(Ah1, B0, a01); a01 = mfma16(Al1, B0, a01);
    a10 = mfma16(Ah0, B1, a10); a10 = mfma16(Al0, B1, a10);
    a11 = mfma16(Ah1, B1, a11); a11 = mfma16(Al1, B1, a11);
    if (wv == 0) {
      short8 B2 = *(const short8*)(bb + 2048);
      a20 = mfma16(Ah0, B2, a20); a20 = mfma16(Al0, B2, a20);
      a21 = mfma16(Ah1, B2, a21); a21 = mfma16(Al1, B2, a21);
    }
  }

  // --- store: Y1T[b][iy][ix][ch32] bf16, ix = f*16+nn, o = h*16+q*4+reg ---
  char* yp = ws + Y1T_OFF + (size_t)(b * 130 + iy) * Y1T_ROWB;
  auto st = [&](int f, f32x4 v0, f32x4 v1) {
    int ix = f * 16 + nn;
    if (ix < 130) {
      uint64_t lo = (uint64_t)packbf(v0[0], v0[1]) | ((uint64_t)packbf(v0[2], v0[3]) << 32);
      uint64_t hi = (uint64_t)packbf(v1[0], v1[1]) | ((uint64_t)packbf(v1[2], v1[3]) << 32);
      *(uint64_t*)(yp + ix * 64 + q * 8) = lo;
      *(uint64_t*)(yp + ix * 64 + 32 + q * 8) = hi;
    }
  };
  st(wv, a00, a01);
  st(wv + 4, a10, a11);
  if (wv == 0) st(8, a20, a21);
}

// ---------------------------------------------------------------------------
// out0: one block per (b, jy); 4 waves x 4 px-frags = 256 px.
__global__ __launch_bounds__(256) void out0_k(const float* __restrict__ x0,
                                              const float* __restrict__ b0,
                                              const float* __restrict__ gg,
                                              const char* __restrict__ ws,
                                              float* __restrict__ out) {
  // x0s: ch-octet planes [ql 2][row 5][col 264][ch 8] bf16; col s <-> gx = s-2
  __shared__ __align__(16) uint16_t x0s[2 * 5 * 264 * 8];   // 42,240 B
  // y1s: planes [q 4][ry 2][col 132][ch 8] bf16; ry 0/1 <-> y1 rows uy+1/uy+2
  __shared__ __align__(16) uint16_t y1s[4 * 2 * 132 * 8];   // 16,896 B
  int tid = threadIdx.x;
  int b = blockIdx.x >> 8, jy = blockIdx.x & 255;

  { // stage x0 (fp32 -> bf16, transpose to [col][ch])
    const float* x0b = x0 + (size_t)b * 1048576;
    for (int e = tid; e < 5200; e += 256) {
      int r = e / 1040, rem = e % 1040;
      int cp = rem % 130, chp = rem / 130;
      int ch0 = chp * 2;
      int s0 = cp * 2;
      int gx0 = s0 - 2;
      int gy = jy + r - 2;
      float v00 = 0.f, v01 = 0.f, v10 = 0.f, v11 = 0.f;
      if ((unsigned)gy < 256u) {
        const float* r0 = x0b + (size_t)ch0 * 65536 + gy * 256;
        const float* r1 = r0 + 65536;
        if ((unsigned)gx0 < 256u)       { v00 = r0[gx0];     v10 = r1[gx0]; }
        if ((unsigned)(gx0 + 1) < 256u) { v01 = r0[gx0 + 1]; v11 = r1[gx0 + 1]; }
      }
      uint16_t* base = x0s + (ch0 >> 3) * 10560 + (r * 264 + s0) * 8 + (ch0 & 7);
      *(uint32_t*)base       = packbf(v00, v10);
      *(uint32_t*)(base + 8) = packbf(v01, v11);
    }
  }
  { // stage y1 rows uy+1, uy+2 (bf16 copy into planes)
    const char* y1tb = ws + Y1T_OFF;
    int uy = jy >> 1;
    for (int e = tid; e < 1040; e += 256) {
      int ry = e / 520, rem = e % 520;
      int c = rem >> 2, qq = rem & 3;
      short8 v = *(const short8*)(y1tb + ((size_t)(b * 130 + uy + 1 + ry) * 132 + c) * 64 + qq * 16);
      *(short8*)(y1s + qq * 2112 + (ry * 132 + c) * 8) = v;
    }
  }
  __syncthreads();

  int lane = tid & 63, wv = tid >> 6;
  int nn = lane & 15, q = lane >> 4, qh = q >> 1, ql = q & 1;
  const char* ab0 = ws + AB0_OFF;
  f32x4 acc[4];
  #pragma unroll
  for (int i = 0; i < 4; ++i) { acc[i][0]=0.f; acc[i][1]=0.f; acc[i][2]=0.f; acc[i][3]=0.f; }

  const uint16_t* xsl = x0s + ql * 10560;
  const uint16_t* ysl = y1s + q * 2112;
  int pxb = wv * 64 + nn;

  // --- G00 5x5 (center zeroed), tap-pair chunks ---
  #pragma unroll
  for (int c = 0; c < 13; ++c) {
    short8 A = *(const short8*)(ab0 + c * 1024 + lane * 16);
    const int tA = 2 * c;
    const int tB = (2 * c + 1 > 24) ? 24 : 2 * c + 1;
    const int offA = ((tA / 5) * 264 + (tA % 5)) * 8;
    const int offB = ((tB / 5) * 264 + (tB % 5)) * 8;
    int toff = qh ? offB : offA;
    const uint16_t* base = xsl + toff + pxb * 8;
    short8 B0 = *(const short8*)(base);
    short8 B1 = *(const short8*)(base + 128);
    short8 B2 = *(const short8*)(base + 256);
    short8 B3 = *(const short8*)(base + 384);
    acc[0] = mfma16(A, B0, acc[0]);
    acc[1] = mfma16(A, B1, acc[1]);
    acc[2] = mfma16(A, B2, acc[2]);
    acc[3] = mfma16(A, B3, acc[3]);
  }

  // --- T10^T(Y1): compact cols + parity masks; rows fixed by jy parity ---
  {
    const short8 z8 = {0,0,0,0,0,0,0,0};
    if ((jy & 1) == 0) {
      #pragma unroll
      for (int bx = 0; bx < 3; ++bx) {
        short8 A = *(const short8*)(ab0 + (16 + bx) * 1024 + lane * 16);
        bool keep = (((nn + 3 - bx) & 1) == 0);
        int cb = (nn + 3 - bx) >> 1;
        const uint16_t* base = ysl + (cb + wv * 32) * 8;   // ry = 0
        short8 B0 = *(const short8*)(base);
        short8 B1 = *(const short8*)(base + 64);
        short8 B2 = *(const short8*)(base + 128);
        short8 B3 = *(const short8*)(base + 192);
        if (!keep) { B0 = z8; B1 = z8; B2 = z8; B3 = z8; }
        acc[0] = mfma16(A, B0, acc[0]);
        acc[1] = mfma16(A, B1, acc[1]);
        acc[2] = mfma16(A, B2, acc[2]);
        acc[3] = mfma16(A, B3, acc[3]);
      }
    } else {
      #pragma unroll
      for (int s = 0; s < 2; ++s) {          // s=0: by=0 (ry=1); s=1: by=2 (ry=0)
        const int chunkb = s ? 19 : 13;
        const int rybase = s ? 0 : 1;
        #pragma unroll
        for (int bx = 0; bx < 3; ++bx) {
          short8 A = *(const short8*)(ab0 + (chunkb + bx) * 1024 + lane * 16);
          bool keep = (((nn + 3 - bx) & 1) == 0);
          int cb = (nn + 3 - bx) >> 1;
          const uint16_t* base = ysl + (rybase * 132 + cb + wv * 32) * 8;
          short8 B0 = *(const short8*)(base);
          short8 B1 = *(const short8*)(base + 64);
          short8 B2 = *(const short8*)(base + 128);
          short8 B3 = *(const short8*)(base + 192);
          if (!keep) { B0 = z8; B1 = z8; B2 = z8; B3 = z8; }
          acc[0] = mfma16(A, B0, acc[0]);
          acc[1] = mfma16(A, B1, acc[1]);
          acc[2] = mfma16(A, B2, acc[2]);
          acc[3] = mfma16(A, B3, acc[3]);
        }
      }
    }
  }

  // --- hollow center: -G10c[jy-parity][px-parity], column-parity masked ---
  {
    const short8 z8 = {0,0,0,0,0,0,0,0};
    short8 A = *(const short8*)(ab0 + (22 + (jy & 1)) * 1024 + lane * 16);
    const uint16_t* base = xsl + (2 * 264 + 2) * 8 + pxb * 8;
    short8 B0 = *(const short8*)(base);
    short8 B1 = *(const short8*)(base + 128);
    short8 B2 = *(const short8*)(base + 256);
    short8 B3 = *(const short8*)(base + 384);
    bool keep = ((nn & 1) == qh);     // k<16 rows multiply even px, k>=16 odd px
    if (!keep) { B0 = z8; B1 = z8; B2 = z8; B3 = z8; }
    acc[0] = mfma16(A, B0, acc[0]);
    acc[1] = mfma16(A, B1, acc[1]);
    acc[2] = mfma16(A, B2, acc[2]);
    acc[3] = mfma16(A, B3, acc[3]);
  }

  // --- epilogue: out = b0_hat*g0 - acc ---
  float rs0 = gg[0] / sqrtf(((const float*)(ws + SUM_OFF))[0]);
  #pragma unroll
  for (int i = 0; i < 4; ++i) {
    int px = wv * 64 + i * 16 + nn;
    #pragma unroll
    for (int reg = 0; reg < 4; ++reg) {
      int m = q * 4 + reg;
      size_t boff = ((size_t)m * 256 + jy) * 256 + px;
      out[((size_t)(b * 16 + m) * 256 + jy) * 256 + px] = b0[boff] * rs0 - acc[i][reg];
    }
  }
}

// ---------------------------------------------------------------------------
// out1: one block per (b, jy); 4 waves x 2 px-frags = 128 px; M=32 (2 blocks).
__global__ __launch_bounds__(256) void out1_k(const float* __restrict__ b1,
                                              const float* __restrict__ gg,
                                              const char* __restrict__ ws,
                                              float* __restrict__ out) {
  __shared__ __align__(16) uint16_t ys[4 * 3 * 132 * 8];   // 25,344 B
  __shared__ __align__(16) uint16_t x1s[4 * 128 * 8];      // 8,192 B
  int tid = threadIdx.x;
  int b = blockIdx.x >> 7, jy = blockIdx.x & 127;
  const char* y1tb = ws + Y1T_OFF;
  const char* x1tb = ws + X1T_OFF;
  for (int e = tid; e < 1584; e += 256) {
    int row = e / 528, rr = e % 528, c = rr >> 2, qq = rr & 3;
    short8 v = *(const short8*)(y1tb + ((size_t)(b * 130 + jy + row) * 132 + c) * 64 + qq * 16);
    *(short8*)(ys + qq * 3168 + (row * 132 + c) * 8) = v;
  }
  for (int e = tid; e < 512; e += 256) {
    int c = e >> 2, qq = e & 3;
    short8 v = *(const short8*)(x1tb + ((size_t)(b * 128 + jy) * 128 + c) * 64 + qq * 16);
    *(short8*)(x1s + qq * 1024 + c * 8) = v;
  }
  __syncthreads();

  int lane = tid & 63, wv = tid >> 6;
  int nn = lane & 15, q = lane >> 4;
  const char* ab1 = ws + AB1_OFF;
  f32x4 acc[2][2];
  #pragma unroll
  for (int i = 0; i < 2; ++i)
    #pragma unroll
    for (int h = 0; h < 2; ++h) { acc[i][h][0]=0.f; acc[i][h][1]=0.f; acc[i][h][2]=0.f; acc[i][h][3]=0.f; }

  const uint16_t* ysl = ys + q * 3168;
  const uint16_t* xsl = x1s + q * 1024;
  int pxb = wv * 32 + nn;

  #pragma unroll
  for (int t = 0; t < 9; ++t) {
    const int ay = t / 3, ax = t % 3;
    short8 A0 = *(const short8*)(ab1 + (t * 2 + 0) * 1024 + lane * 16);
    short8 A1 = *(const short8*)(ab1 + (t * 2 + 1) * 1024 + lane * 16);
    const uint16_t* base = ysl + ((2 - ay) * 132 + (2 - ax) + pxb) * 8;
    short8 B0 = *(const short8*)(base);
    short8 B1 = *(const short8*)(base + 128);
    acc[0][0] = mfma16(A0, B0, acc[0][0]);
    acc[0][1] = mfma16(A1, B0, acc[0][1]);
    acc[1][0] = mfma16(A0, B1, acc[1][0]);
    acc[1][1] = mfma16(A1, B1, acc[1][1]);
  }
  { // -sub1 blockdiag * x1
    short8 A0 = *(const short8*)(ab1 + 18 * 1024 + lane * 16);
    short8 A1 = *(const short8*)(ab1 + 19 * 1024 + lane * 16);
    const uint16_t* base = xsl + pxb * 8;
    short8 B0 = *(const short8*)(base);
    short8 B1 = *(const short8*)(base + 128);
    acc[0][0] = mfma16(A0, B0, acc[0][0]);
    acc[0][1] = mfma16(A1, B0, acc[0][1]);
    acc[1][0] = mfma16(A0, B1, acc[1][0]);
    acc[1][1] = mfma16(A1, B1, acc[1][1]);
  }

  float rs1 = gg[1] / sqrtf(((const float*)(ws + SUM_OFF))[1]);
  #pragma unroll
  for (int i = 0; i < 2; ++i) {
    int px = wv * 32 + i * 16 + nn;
    #pragma unroll
    for (int h = 0; h < 2; ++h)
      #pragma unroll
      for (int reg = 0; reg < 4; ++reg) {
        int m = h * 16 + q * 4 + reg;
        size_t boff = ((size_t)m * 128 + jy) * 128 + px;
        out[16777216 + ((size_t)(b * 32 + m) * 128 + jy) * 128 + px] = b1[boff] * rs1 - acc[i][h][reg];
      }
  }
}

// ---------------------------------------------------------------------------
extern "C" void kernel_launch(void* const* d_in, const int* in_sizes, int n_in,
                              void* d_out, int out_size, void* d_ws, size_t ws_size,
                              hipStream_t stream) {
  const float* x0  = (const float*)d_in[0];
  const float* x1  = (const float*)d_in[1];
  const float* W00 = (const float*)d_in[2];
  const float* W10 = (const float*)d_in[3];
  const float* W11 = (const float*)d_in[4];
  const float* b0  = (const float*)d_in[5];
  const float* b1  = (const float*)d_in[6];
  const float* g   = (const float*)d_in[7];
  float* out = (float*)d_out;
  char* ws   = (char*)d_ws;

  blob_k<<<200, 256, 0, stream>>>(W00, W10, W11, ws);
  sumsq_k<<<512, 256, 0, stream>>>(b0, 16 * 256 * 256, (float*)(ws + SUM_OFF));
  sumsq_k<<<512, 256, 0, stream>>>(b1, 32 * 128 * 128, (float*)(ws + SUM_OFF) + 1);
  x1t_k<<<2048, 256, 0, stream>>>(x1, ws);
  y1m_k<<<16 * 130, 256, 0, stream>>>(x0, ws);
  out0_k<<<4096, 256, 0, stream>>>(x0, b0, g, ws, out);
  out1_k<<<2048, 256, 0, stream>>>(b1, g, ws, out);
}

// Round 4
// 430.591 us; speedup vs baseline: 1.5619x; 1.1162x over previous
//
#include <hip/hip_runtime.h>
#include <stdint.h>

// ---------------------------------------------------------------------------
// MultiMonotoneHollowConv, round 5: out0_k restructured for occupancy + LDS.
//   out0 = -( G00(5x5,center->-G10c[phase]) * x0  +  T10^T(Y1)  - b0^*g0 )
//   out1 = -( W11^T(3x3) * Y1  -  sub1_blockdiag * x1  - b1^*g1 )
//   Y1   = conv(x0,W10,s2,p3) + conv(x1,W11,s1,p2)   [MFMA bf16,
//          weights split hi+lo bf16 so only x carries bf16 rounding]
// out0_k: half-row blocks (128 px), LDS 29.6 KB -> 5 blocks/CU (was 2);
//   x0 staging = one ds_write_b128 per lane-task (conflict-free; was 16-way).
// MFMA frag layouts (gfx950, HW-verified per guide):
//   A[m=lane&15][k=quad*8+j], B[k=quad*8+j][n=lane&15], D: row m=quad*4+reg,
//   col n=lane&15.  K-chunks use ch-octet LDS planes so each B-frag is one
//   conflict-free ds_read_b128.
// ---------------------------------------------------------------------------

using short8 = __attribute__((ext_vector_type(8))) short;
using f32x4  = __attribute__((ext_vector_type(4))) float;

#define B_ 16

// workspace byte offsets (total ~34.45 MB; must stay < ~35.1 MB proven safe)
static constexpr size_t Y1T_OFF  = 0;                        // [16][130][132][32] bf16
static constexpr size_t Y1T_ROWB = 132 * 64;                 // 8448 B per (b,iy) row
static constexpr size_t X1T_OFF  = (size_t)16 * 130 * 132 * 64;        // 17,571,840
static constexpr size_t AB0_OFF  = X1T_OFF + (size_t)16 * 128 * 128 * 64; // +16,777,216
static constexpr size_t AB1_OFF  = AB0_OFF + 24 * 1024;     // blob0: 24 chunks
static constexpr size_t SUM_OFF  = AB1_OFF + 20 * 1024;     // blob1: 10 chunks x 2
static constexpr size_t AB2_OFF  = SUM_OFF + 1024;          // y1 fwd weights: 56 chunks

__device__ __forceinline__ uint32_t bf16rne(float v) {
  uint32_t u = __float_as_uint(v);
  return (u + 0x7fffu + ((u >> 16) & 1u)) >> 16;
}
__device__ __forceinline__ uint32_t packbf(float lo, float hi) {
  return bf16rne(lo) | (bf16rne(hi) << 16);
}
__device__ __forceinline__ f32x4 mfma16(short8 a, short8 b, f32x4 c) {
  return __builtin_amdgcn_mfma_f32_16x16x32_bf16(a, b, c, 0, 0, 0);
}

// ---------------------------------------------------------------------------
// Weight blobs in exact A-fragment order (bf16), plus zero the norm sums.
// blob0 (out0): [0..12] G00 tap-pairs (k=tap_sub*16+ch), center tap zeroed;
//               [13..21] W10t taps (k=o);  [22,23] -G10c parity chunks (py=0,1;
//               k<16 even-px rows, k>=16 odd-px rows).
// blob1 (out1): [t=0..8][h=0,1] W11 taps (k=o, m=h*16+..); [9][h] -sub1 blockdiag.
// blob2 (y1 fwd): [t 0..8][h][part hi/lo] W11 fwd (k=in ch, m=out ch h*16+..)
//                 then [c5 0..4][h][part] W10 fwd tap-pairs (k=qh*16+ich,
//                 tap = 2*c5+qh, tap 9 zero-padded).
__global__ void blob_k(const float* __restrict__ W00, const float* __restrict__ W10,
                       const float* __restrict__ W11, char* __restrict__ ws) {
  int e = blockIdx.x * 256 + threadIdx.x;
  if (e < 2) ((float*)(ws + SUM_OFF))[e] = 0.f;
  if (e < 12288) {
    int chunk = e >> 9, le = e & 511, lane = le >> 3, j = le & 7;
    int q = lane >> 4, m = lane & 15;
    float val = 0.f;
    if (chunk < 13) {
      int t = 2 * chunk + (q >> 1);
      int n = ((q & 1) << 3) + j;
      if (t <= 24 && t != 12) {
        int dy = t / 5 - 2, dx = t % 5 - 2;
        for (int o = 0; o < 16; ++o) {
          const float* wm = W00 + (o * 16 + m) * 9;
          const float* wn = W00 + (o * 16 + n) * 9;
          for (int ay = 0; ay < 3; ++ay) {
            int ay2 = ay + dy; if ((unsigned)ay2 > 2u) continue;
            for (int ax = 0; ax < 3; ++ax) {
              int ax2 = ax + dx; if ((unsigned)ax2 > 2u) continue;
              val += wm[ay * 3 + ax] * wn[ay2 * 3 + ax2];
            }
          }
        }
      }
    } else if (chunk < 22) {
      int tap = chunk - 13;
      int o = ((lane >> 4) << 3) + j;      // k = q*8+j
      val = W10[(o * 16 + m) * 9 + tap];
    } else {
      int py = chunk - 22;
      int k = ((lane >> 4) << 3) + j;
      int par = k >> 4, n = k & 15;
      for (int o = 0; o < 32; ++o) {
        const float* wn = W10 + (o * 16 + n) * 9;
        const float* wm = W10 + (o * 16 + m) * 9;
        for (int by = 0; by < 3; ++by) {
          if ((py == 0) ? (by != 1) : (by == 1)) continue;
          for (int bx = 0; bx < 3; ++bx) {
            if ((par == 0) ? (bx != 1) : (bx == 1)) continue;
            val -= wn[by * 3 + bx] * wm[by * 3 + bx];
          }
        }
      }
    }
    ((uint16_t*)(ws + AB0_OFF))[chunk * 512 + lane * 8 + j] = (uint16_t)bf16rne(val);
  } else if (e < 12288 + 10240) {
    int e2 = e - 12288;
    int chunk = e2 >> 10, r = e2 & 1023, h = r >> 9, le = r & 511;
    int lane = le >> 3, j = le & 7;
    int m = h * 16 + (lane & 15);
    int kk = ((lane >> 4) << 3) + j;      // k = q*8+j
    float val = 0.f;
    if (chunk < 9) {
      val = W11[(kk * 32 + m) * 9 + chunk];      // o = kk, tap = chunk
    } else if ((kk >> 4) == h) {
      int np = kk & 15;
      float s = 0.f;
      for (int o = 0; o < 32; ++o)
        for (int t = 0; t < 9; ++t)
          s += W11[(o * 32 + m) * 9 + t] * W11[(o * 32 + h * 16 + np) * 9 + t];
      val = -s;
    }
    ((uint16_t*)(ws + AB1_OFF))[(chunk * 2 + h) * 512 + lane * 8 + j] = (uint16_t)bf16rne(val);
  } else if (e < 12288 + 10240 + 28672) {
    int e3 = e - 22528;
    int chunk = e3 >> 9, le = e3 & 511;
    int lane = le >> 3, j = le & 7;
    int q = lane >> 4, m = lane & 15;
    int k = q * 8 + j;
    int part;
    float val = 0.f;
    if (chunk < 36) {
      int t = chunk >> 2, h = (chunk >> 1) & 1;
      part = chunk & 1;
      int o = h * 16 + m;
      val = W11[(o * 32 + k) * 9 + t];           // fwd: A[m=o][k=ich]
    } else {
      int c2 = chunk - 36;
      int c5 = c2 >> 2, h = (c2 >> 1) & 1;
      part = c2 & 1;
      int tap = 2 * c5 + (k >> 4);
      int o = h * 16 + m;
      if (tap <= 8) val = W10[(o * 16 + (k & 15)) * 9 + tap];
    }
    uint32_t hi = bf16rne(val);
    uint16_t outv;
    if (part == 0) outv = (uint16_t)hi;
    else outv = (uint16_t)bf16rne(val - __uint_as_float(hi << 16));
    ((uint16_t*)(ws + AB2_OFF))[chunk * 512 + lane * 8 + j] = outv;
  }
}

// ---------------------------------------------------------------------------
__global__ void sumsq_k(const float* __restrict__ src, int n, float* __restrict__ dst) {
  float s = 0.f;
  for (int i = blockIdx.x * blockDim.x + threadIdx.x; i < n; i += gridDim.x * blockDim.x) {
    float v = src[i];
    s += v * v;
  }
  #pragma unroll
  for (int off = 32; off > 0; off >>= 1) s += __shfl_down(s, off, 64);
  if ((threadIdx.x & 63) == 0) atomicAdd(dst, s);
}

// ---------------------------------------------------------------------------
// x1t[b][r][c][ch] = bf16(x1[b][ch][r][c])
__global__ __launch_bounds__(256) void x1t_k(const float* __restrict__ x1, char* __restrict__ ws) {
  __shared__ __align__(16) uint16_t tmp[128 * 32];
  int b = blockIdx.x >> 7, r = blockIdx.x & 127;
  int tid = threadIdx.x;
  for (int e = tid; e < 4096; e += 256) {
    int ch = e >> 7, c = e & 127;
    float v = x1[((size_t)(b * 32 + ch) * 128 + r) * 128 + c];
    tmp[c * 32 + ch] = (uint16_t)bf16rne(v);
  }
  __syncthreads();
  char* dst = ws + X1T_OFF + ((size_t)(b * 128 + r) * 128) * 64;
  for (int e = tid; e < 512; e += 256)
    *(short8*)(dst + e * 16) = *(const short8*)((const char*)tmp + e * 16);
}

// ---------------------------------------------------------------------------
// Y1 via MFMA: one block per (b, iy); 4 waves; 9 px-frags of 16 (130 used).
// LDS x0s: [ql 2][row 3][par 2][half-col 146][ch8] bf16 (col = 2h+p-3),
//          so stride-2 taps become unit-stride ds_read_b128.
// LDS x1s: [q 4][row 3][col 148][ch8] bf16 (col cs <-> x1 col cs-2).
// Weights from AB2 blob: hi+lo bf16 pairs -> only x carries bf16 rounding.
__global__ __launch_bounds__(256) void y1m_k(const float* __restrict__ x0,
                                             char* __restrict__ ws) {
  __shared__ __align__(16) uint16_t x0s[2 * 3 * 2 * 146 * 8];   // 28,032 B
  __shared__ __align__(16) uint16_t x1s[4 * 3 * 148 * 8];       // 28,416 B
  int tid = threadIdx.x;
  int b = blockIdx.x / 130, iy = blockIdx.x % 130;

  { // zero-fill both tiles (covers all pads / OOB rows)
    uint4 z = make_uint4(0u, 0u, 0u, 0u);
    for (int e = tid; e < 1752; e += 256) ((uint4*)x0s)[e] = z;
    for (int e = tid; e < 1776; e += 256) ((uint4*)x1s)[e] = z;
  }
  __syncthreads();

  { // stage x0 rows 2iy-3..2iy-1 (fp32 -> bf16, even/odd col split)
    const float* x0b = x0 + (size_t)b * 1048576;
    for (int e = tid; e < 6144; e += 256) {
      int r = e >> 11;            // 0..2
      int ch0 = ((e >> 8) & 7) * 2;
      int c = e & 255;
      int gy = 2 * iy + r - 3;
      float v0 = 0.f, v1 = 0.f;
      if ((unsigned)gy < 256u) {
        const float* rp = x0b + (size_t)ch0 * 65536 + (size_t)gy * 256 + c;
        v0 = rp[0]; v1 = rp[65536];
      }
      int sc = c + 3, p = sc & 1, hc = sc >> 1;
      *(uint32_t*)((char*)x0s + ((((ch0 >> 3) * 3 + r) * 2 + p) * 146 + hc) * 16 + (ch0 & 7) * 2)
          = packbf(v0, v1);
    }
  }
  { // stage x1 rows iy-2..iy (bf16 copy from x1t, shifted +2 cols)
    const char* x1tb = ws + X1T_OFF;
    for (int e = tid; e < 1536; e += 256) {
      int row = e >> 9, rr = e & 511, c = rr >> 2, qq = rr & 3;
      int gy = iy + row - 2;
      if ((unsigned)gy < 128u) {
        short8 v = *(const short8*)(x1tb + ((size_t)(b * 128 + gy) * 128 + c) * 64 + qq * 16);
        *(short8*)((char*)x1s + ((qq * 3 + row) * 148 + (c + 2)) * 16) = v;
      }
    }
  }
  __syncthreads();

  int lane = tid & 63, wv = tid >> 6;
  int nn = lane & 15, q = lane >> 4, qh = q >> 1, ql = q & 1;
  const char* ab2 = ws + AB2_OFF;

  f32x4 a00 = {0.f,0.f,0.f,0.f}, a01 = {0.f,0.f,0.f,0.f};
  f32x4 a10 = {0.f,0.f,0.f,0.f}, a11 = {0.f,0.f,0.f,0.f};
  f32x4 a20 = {0.f,0.f,0.f,0.f}, a21 = {0.f,0.f,0.f,0.f};

  // --- W11 fwd (s1,p2): 9 taps, K=32 in-ch ---
  #pragma unroll
  for (int t = 0; t < 9; ++t) {
    const int ay = t / 3, ax = t % 3;
    const char* cb = ab2 + t * 4096 + lane * 16;
    short8 Ah0 = *(const short8*)(cb);
    short8 Al0 = *(const short8*)(cb + 1024);
    short8 Ah1 = *(const short8*)(cb + 2048);
    short8 Al1 = *(const short8*)(cb + 3072);
    const char* bb = (const char*)x1s + ((q * 3 + ay) * 148 + ax + nn) * 16 + wv * 256;
    short8 B0 = *(const short8*)(bb);            // frag wv
    short8 B1 = *(const short8*)(bb + 1024);     // frag wv+4
    a00 = mfma16(Ah0, B0, a00); a00 = mfma16(Al0, B0, a00);
    a01 = mfma16(Ah1, B0, a01); a01 = mfma16(Al1, B0, a01);
    a10 = mfma16(Ah0, B1, a10); a10 = mfma16(Al0, B1, a10);
    a11 = mfma16(Ah1, B1, a11); a11 = mfma16(Al1, B1, a11);
    if (wv == 0) {
      short8 B2 = *(const short8*)(bb + 2048);   // frag 8
      a20 = mfma16(Ah0, B2, a20); a20 = mfma16(Al0, B2, a20);
      a21 = mfma16(Ah1, B2, a21); a21 = mfma16(Al1, B2, a21);
    }
  }

  // --- W10 fwd (s2,p3): tap-pair chunks, k = qh*16 + ich ---
  #pragma unroll
  for (int c5 = 0; c5 < 5; ++c5) {
    const char* cb = ab2 + (36 + c5 * 4) * 1024 + lane * 16;
    short8 Ah0 = *(const short8*)(cb);
    short8 Al0 = *(const short8*)(cb + 1024);
    short8 Ah1 = *(const short8*)(cb + 2048);
    short8 Al1 = *(const short8*)(cb + 3072);
    int tl = 2 * c5 + qh; if (tl > 8) tl = 8;    // tap 9 zero-padded in A
    int by = tl / 3, bx = tl % 3;
    int p = bx & 1, hb = bx >> 1;
    const char* bb = (const char*)x0s + ((((ql * 3 + by) * 2 + p) * 146) + hb + nn) * 16 + wv * 256;
    short8 B0 = *(const short8*)(bb);
    short8 B1 = *(const short8*)(bb + 1024);
    a00 = mfma16(Ah0, B0, a00); a00 = mfma16(Al0, B0, a00);
    a01 = mfma16(Ah1, B0, a01); a01 = mfma16(Al1, B0, a01);
    a10 = mfma16(Ah0, B1, a10); a10 = mfma16(Al0, B1, a10);
    a11 = mfma16(Ah1, B1, a11); a11 = mfma16(Al1, B1, a11);
    if (wv == 0) {
      short8 B2 = *(const short8*)(bb + 2048);
      a20 = mfma16(Ah0, B2, a20); a20 = mfma16(Al0, B2, a20);
      a21 = mfma16(Ah1, B2, a21); a21 = mfma16(Al1, B2, a21);
    }
  }

  // --- store: Y1T[b][iy][ix][ch32] bf16, ix = f*16+nn, o = h*16+q*4+reg ---
  char* yp = ws + Y1T_OFF + (size_t)(b * 130 + iy) * Y1T_ROWB;
  auto st = [&](int f, f32x4 v0, f32x4 v1) {
    int ix = f * 16 + nn;
    if (ix < 130) {
      uint64_t lo = (uint64_t)packbf(v0[0], v0[1]) | ((uint64_t)packbf(v0[2], v0[3]) << 32);
      uint64_t hi = (uint64_t)packbf(v1[0], v1[1]) | ((uint64_t)packbf(v1[2], v1[3]) << 32);
      *(uint64_t*)(yp + ix * 64 + q * 8) = lo;
      *(uint64_t*)(yp + ix * 64 + 32 + q * 8) = hi;
    }
  };
  st(wv, a00, a01);
  st(wv + 4, a10, a11);
  if (wv == 0) st(8, a20, a21);
}

// ---------------------------------------------------------------------------
// out0: one block per (b, jy, half); 4 waves x 2 px-frags = 128 px.
// LDS 29.6 KB -> 5 blocks/CU. x0 staged as one ds_write_b128 per lane-task
// (coalesced 256B global reads per instr, conflict-free LDS writes).
__global__ __launch_bounds__(256, 5) void out0_k(const float* __restrict__ x0,
                                                 const float* __restrict__ b0,
                                                 const float* __restrict__ gg,
                                                 const char* __restrict__ ws,
                                                 float* __restrict__ out) {
  // x0s: [oct 2][row 5][col 132][ch 8] bf16; col c <-> gx = jx_base + c - 2
  __shared__ __align__(16) uint16_t x0s[2 * 5 * 132 * 8];   // 21,120 B
  // y1s: [q 4][ry 2][col 66][ch 8] bf16; ry 0/1 <-> y1 rows uy+1/uy+2,
  //      col lc <-> y1 col jx_base/2 + lc
  __shared__ __align__(16) uint16_t y1s[4 * 2 * 66 * 8];    // 8,448 B
  int tid = threadIdx.x;
  int b = blockIdx.x >> 9, jy = (blockIdx.x >> 1) & 255;
  int jx_base = (blockIdx.x & 1) << 7;

  { // stage x0: one 16B ch-octet granule per task
    const float* x0b = x0 + (size_t)b * 1048576;
    for (int e = tid; e < 1320; e += 256) {
      int c = e % 132, rr = e / 132, r = rr % 5, oct = rr / 5;
      int gy = jy + r - 2, gx = jx_base + c - 2;
      uint32_t w0 = 0u, w1 = 0u, w2 = 0u, w3 = 0u;
      if ((unsigned)gy < 256u && (unsigned)gx < 256u) {
        const float* p = x0b + (size_t)(oct * 8) * 65536 + gy * 256 + gx;
        w0 = packbf(p[0],      p[65536]);
        w1 = packbf(p[131072], p[196608]);
        w2 = packbf(p[262144], p[327680]);
        w3 = packbf(p[393216], p[458752]);
      }
      *(uint4*)((char*)x0s + (size_t)e * 16) = make_uint4(w0, w1, w2, w3);
    }
  }
  { // stage y1 rows uy+1, uy+2 (bf16 copy into q-planes)
    const char* y1tb = ws + Y1T_OFF;
    int uy = jy >> 1, c0 = jx_base >> 1;
    for (int e = tid; e < 528; e += 256) {
      int qq = e & 3, t = e >> 2, lc = t % 66, ry = t / 66;
      short8 v = *(const short8*)(y1tb +
          ((size_t)(b * 130 + uy + 1 + ry) * 132 + c0 + lc) * 64 + qq * 16);
      *(short8*)((char*)y1s + ((size_t)(qq * 2 + ry) * 66 + lc) * 16) = v;
    }
  }
  __syncthreads();

  int lane = tid & 63, wv = tid >> 6;
  int nn = lane & 15, q = lane >> 4, qh = q >> 1, ql = q & 1;
  const char* ab0 = ws + AB0_OFF;
  f32x4 acc[2];
  #pragma unroll
  for (int i = 0; i < 2; ++i) { acc[i][0]=0.f; acc[i][1]=0.f; acc[i][2]=0.f; acc[i][3]=0.f; }

  const uint16_t* xsl = x0s + ql * 5280;   // oct plane (5*132*8)
  const uint16_t* ysl = y1s + q * 1056;    // q plane (2*66*8)
  int pxb = wv * 32 + nn;

  // --- G00 5x5 (center zeroed), tap-pair chunks ---
  #pragma unroll
  for (int c = 0; c < 13; ++c) {
    short8 A = *(const short8*)(ab0 + c * 1024 + lane * 16);
    const int tA = 2 * c;
    const int tB = (2 * c + 1 > 24) ? 24 : 2 * c + 1;
    const int offA = ((tA / 5) * 132 + (tA % 5)) * 8;
    const int offB = ((tB / 5) * 132 + (tB % 5)) * 8;
    int toff = qh ? offB : offA;
    const uint16_t* base = xsl + toff + pxb * 8;
    short8 B0 = *(const short8*)(base);
    short8 B1 = *(const short8*)(base + 128);
    acc[0] = mfma16(A, B0, acc[0]);
    acc[1] = mfma16(A, B1, acc[1]);
  }

  // --- T10^T(Y1): compact cols + parity masks; rows fixed by jy parity ---
  {
    const short8 z8 = {0,0,0,0,0,0,0,0};
    if ((jy & 1) == 0) {
      #pragma unroll
      for (int bx = 0; bx < 3; ++bx) {
        short8 A = *(const short8*)(ab0 + (16 + bx) * 1024 + lane * 16);
        bool keep = (((nn + 3 - bx) & 1) == 0);
        int cb = (nn + 3 - bx) >> 1;
        const uint16_t* base = ysl + (cb + wv * 16) * 8;   // ry = 0
        short8 B0 = *(const short8*)(base);
        short8 B1 = *(const short8*)(base + 64);
        if (!keep) { B0 = z8; B1 = z8; }
        acc[0] = mfma16(A, B0, acc[0]);
        acc[1] = mfma16(A, B1, acc[1]);
      }
    } else {
      #pragma unroll
      for (int s = 0; s < 2; ++s) {          // s=0: by=0 (ry=1); s=1: by=2 (ry=0)
        const int chunkb = s ? 19 : 13;
        const int rybase = s ? 0 : 1;
        #pragma unroll
        for (int bx = 0; bx < 3; ++bx) {
          short8 A = *(const short8*)(ab0 + (chunkb + bx) * 1024 + lane * 16);
          bool keep = (((nn + 3 - bx) & 1) == 0);
          int cb = (nn + 3 - bx) >> 1;
          const uint16_t* base = ysl + (rybase * 66 + cb + wv * 16) * 8;
          short8 B0 = *(const short8*)(base);
          short8 B1 = *(const short8*)(base + 64);
          if (!keep) { B0 = z8; B1 = z8; }
          acc[0] = mfma16(A, B0, acc[0]);
          acc[1] = mfma16(A, B1, acc[1]);
        }
      }
    }
  }

  // --- hollow center: -G10c[jy-parity][px-parity], column-parity masked ---
  {
    const short8 z8 = {0,0,0,0,0,0,0,0};
    short8 A = *(const short8*)(ab0 + (22 + (jy & 1)) * 1024 + lane * 16);
    const uint16_t* base = xsl + (2 * 132 + 2) * 8 + pxb * 8;
    short8 B0 = *(const short8*)(base);
    short8 B1 = *(const short8*)(base + 128);
    bool keep = ((nn & 1) == qh);     // k<16 rows multiply even px, k>=16 odd px
    if (!keep) { B0 = z8; B1 = z8; }
    acc[0] = mfma16(A, B0, acc[0]);
    acc[1] = mfma16(A, B1, acc[1]);
  }

  // --- epilogue: out = b0_hat*g0 - acc ---
  float rs0 = gg[0] / sqrtf(((const float*)(ws + SUM_OFF))[0]);
  #pragma unroll
  for (int i = 0; i < 2; ++i) {
    int px = jx_base + wv * 32 + i * 16 + nn;
    #pragma unroll
    for (int reg = 0; reg < 4; ++reg) {
      int m = q * 4 + reg;
      size_t boff = ((size_t)m * 256 + jy) * 256 + px;
      out[((size_t)(b * 16 + m) * 256 + jy) * 256 + px] = b0[boff] * rs0 - acc[i][reg];
    }
  }
}

// ---------------------------------------------------------------------------
// out1: one block per (b, jy); 4 waves x 2 px-frags = 128 px; M=32 (2 blocks).
__global__ __launch_bounds__(256) void out1_k(const float* __restrict__ b1,
                                              const float* __restrict__ gg,
                                              const char* __restrict__ ws,
                                              float* __restrict__ out) {
  __shared__ __align__(16) uint16_t ys[4 * 3 * 132 * 8];   // 25,344 B
  __shared__ __align__(16) uint16_t x1s[4 * 128 * 8];      // 8,192 B
  int tid = threadIdx.x;
  int b = blockIdx.x >> 7, jy = blockIdx.x & 127;
  const char* y1tb = ws + Y1T_OFF;
  const char* x1tb = ws + X1T_OFF;
  for (int e = tid; e < 1584; e += 256) {
    int row = e / 528, rr = e % 528, c = rr >> 2, qq = rr & 3;
    short8 v = *(const short8*)(y1tb + ((size_t)(b * 130 + jy + row) * 132 + c) * 64 + qq * 16);
    *(short8*)(ys + qq * 3168 + (row * 132 + c) * 8) = v;
  }
  for (int e = tid; e < 512; e += 256) {
    int c = e >> 2, qq = e & 3;
    short8 v = *(const short8*)(x1tb + ((size_t)(b * 128 + jy) * 128 + c) * 64 + qq * 16);
    *(short8*)(x1s + qq * 1024 + c * 8) = v;
  }
  __syncthreads();

  int lane = tid & 63, wv = tid >> 6;
  int nn = lane & 15, q = lane >> 4;
  const char* ab1 = ws + AB1_OFF;
  f32x4 acc[2][2];
  #pragma unroll
  for (int i = 0; i < 2; ++i)
    #pragma unroll
    for (int h = 0; h < 2; ++h) { acc[i][h][0]=0.f; acc[i][h][1]=0.f; acc[i][h][2]=0.f; acc[i][h][3]=0.f; }

  const uint16_t* ysl = ys + q * 3168;
  const uint16_t* xsl = x1s + q * 1024;
  int pxb = wv * 32 + nn;

  #pragma unroll
  for (int t = 0; t < 9; ++t) {
    const int ay = t / 3, ax = t % 3;
    short8 A0 = *(const short8*)(ab1 + (t * 2 + 0) * 1024 + lane * 16);
    short8 A1 = *(const short8*)(ab1 + (t * 2 + 1) * 1024 + lane * 16);
    const uint16_t* base = ysl + ((2 - ay) * 132 + (2 - ax) + pxb) * 8;
    short8 B0 = *(const short8*)(base);
    short8 B1 = *(const short8*)(base + 128);
    acc[0][0] = mfma16(A0, B0, acc[0][0]);
    acc[0][1] = mfma16(A1, B0, acc[0][1]);
    acc[1][0] = mfma16(A0, B1, acc[1][0]);
    acc[1][1] = mfma16(A1, B1, acc[1][1]);
  }
  { // -sub1 blockdiag * x1
    short8 A0 = *(const short8*)(ab1 + 18 * 1024 + lane * 16);
    short8 A1 = *(const short8*)(ab1 + 19 * 1024 + lane * 16);
    const uint16_t* base = xsl + pxb * 8;
    short8 B0 = *(const short8*)(base);
    short8 B1 = *(const short8*)(base + 128);
    acc[0][0] = mfma16(A0, B0, acc[0][0]);
    acc[0][1] = mfma16(A1, B0, acc[0][1]);
    acc[1][0] = mfma16(A0, B1, acc[1][0]);
    acc[1][1] = mfma16(A1, B1, acc[1][1]);
  }

  float rs1 = gg[1] / sqrtf(((const float*)(ws + SUM_OFF))[1]);
  #pragma unroll
  for (int i = 0; i < 2; ++i) {
    int px = wv * 32 + i * 16 + nn;
    #pragma unroll
    for (int h = 0; h < 2; ++h)
      #pragma unroll
      for (int reg = 0; reg < 4; ++reg) {
        int m = h * 16 + q * 4 + reg;
        size_t boff = ((size_t)m * 128 + jy) * 128 + px;
        out[16777216 + ((size_t)(b * 32 + m) * 128 + jy) * 128 + px] = b1[boff] * rs1 - acc[i][h][reg];
      }
  }
}

// ---------------------------------------------------------------------------
extern "C" void kernel_launch(void* const* d_in, const int* in_sizes, int n_in,
                              void* d_out, int out_size, void* d_ws, size_t ws_size,
                              hipStream_t stream) {
  const float* x0  = (const float*)d_in[0];
  const float* x1  = (const float*)d_in[1];
  const float* W00 = (const float*)d_in[2];
  const float* W10 = (const float*)d_in[3];
  const float* W11 = (const float*)d_in[4];
  const float* b0  = (const float*)d_in[5];
  const float* b1  = (const float*)d_in[6];
  const float* g   = (const float*)d_in[7];
  float* out = (float*)d_out;
  char* ws   = (char*)d_ws;

  blob_k<<<200, 256, 0, stream>>>(W00, W10, W11, ws);
  sumsq_k<<<512, 256, 0, stream>>>(b0, 16 * 256 * 256, (float*)(ws + SUM_OFF));
  sumsq_k<<<512, 256, 0, stream>>>(b1, 32 * 128 * 128, (float*)(ws + SUM_OFF) + 1);
  x1t_k<<<2048, 256, 0, stream>>>(x1, ws);
  y1m_k<<<16 * 130, 256, 0, stream>>>(x0, ws);
  out0_k<<<8192, 256, 0, stream>>>(x0, b0, g, ws, out);
  out1_k<<<2048, 256, 0, stream>>>(b1, g, ws, out);
}

// Round 5
// 392.804 us; speedup vs baseline: 1.7121x; 1.0962x over previous
//
#include <hip/hip_runtime.h>
#include <stdint.h>

// ---------------------------------------------------------------------------
// MultiMonotoneHollowConv, round 6: y1m_k sheds the x1 LDS stage.
//   out0 = -( G00(5x5,center->-G10c[phase]) * x0  +  T10^T(Y1)  - b0^*g0 )
//   out1 = -( W11^T(3x3) * Y1  -  sub1_blockdiag * x1  - b1^*g1 )
//   Y1   = conv(x0,W10,s2,p3) + conv(x1,W11,s1,p2)   [MFMA bf16,
//          weights split hi+lo bf16 so only x carries bf16 rounding]
// y1m_k: W11 B-frags read DIRECT from global x1t (already in frag order;
//   24 KB/block -> L1-resident; coalesced 1KB wave reads). LDS 56.8->28.0 KB
//   -> 5 blocks/CU (was 2). W11 section placed before the barrier so it runs
//   while x0 ds_writes drain.
// MFMA frag layouts (gfx950, HW-verified per guide):
//   A[m=lane&15][k=quad*8+j], B[k=quad*8+j][n=lane&15], D: row m=quad*4+reg,
//   col n=lane&15.  K-chunks use ch-octet LDS planes so each B-frag is one
//   conflict-free ds_read_b128.
// ---------------------------------------------------------------------------

using short8 = __attribute__((ext_vector_type(8))) short;
using f32x4  = __attribute__((ext_vector_type(4))) float;

#define B_ 16

// workspace byte offsets (total ~34.45 MB; must stay < ~35.1 MB proven safe)
static constexpr size_t Y1T_OFF  = 0;                        // [16][130][132][32] bf16
static constexpr size_t Y1T_ROWB = 132 * 64;                 // 8448 B per (b,iy) row
static constexpr size_t X1T_OFF  = (size_t)16 * 130 * 132 * 64;        // 17,571,840
static constexpr size_t AB0_OFF  = X1T_OFF + (size_t)16 * 128 * 128 * 64; // +16,777,216
static constexpr size_t AB1_OFF  = AB0_OFF + 24 * 1024;     // blob0: 24 chunks
static constexpr size_t SUM_OFF  = AB1_OFF + 20 * 1024;     // blob1: 10 chunks x 2
static constexpr size_t AB2_OFF  = SUM_OFF + 1024;          // y1 fwd weights: 56 chunks

__device__ __forceinline__ uint32_t bf16rne(float v) {
  uint32_t u = __float_as_uint(v);
  return (u + 0x7fffu + ((u >> 16) & 1u)) >> 16;
}
__device__ __forceinline__ uint32_t packbf(float lo, float hi) {
  return bf16rne(lo) | (bf16rne(hi) << 16);
}
__device__ __forceinline__ f32x4 mfma16(short8 a, short8 b, f32x4 c) {
  return __builtin_amdgcn_mfma_f32_16x16x32_bf16(a, b, c, 0, 0, 0);
}

// ---------------------------------------------------------------------------
// Weight blobs in exact A-fragment order (bf16), plus zero the norm sums.
// blob0 (out0): [0..12] G00 tap-pairs (k=tap_sub*16+ch), center tap zeroed;
//               [13..21] W10t taps (k=o);  [22,23] -G10c parity chunks (py=0,1;
//               k<16 even-px rows, k>=16 odd-px rows).
// blob1 (out1): [t=0..8][h=0,1] W11 taps (k=o, m=h*16+..); [9][h] -sub1 blockdiag.
// blob2 (y1 fwd): [t 0..8][h][part hi/lo] W11 fwd (k=in ch, m=out ch h*16+..)
//                 then [c5 0..4][h][part] W10 fwd tap-pairs (k=qh*16+ich,
//                 tap = 2*c5+qh, tap 9 zero-padded).
__global__ void blob_k(const float* __restrict__ W00, const float* __restrict__ W10,
                       const float* __restrict__ W11, char* __restrict__ ws) {
  int e = blockIdx.x * 256 + threadIdx.x;
  if (e < 2) ((float*)(ws + SUM_OFF))[e] = 0.f;
  if (e < 12288) {
    int chunk = e >> 9, le = e & 511, lane = le >> 3, j = le & 7;
    int q = lane >> 4, m = lane & 15;
    float val = 0.f;
    if (chunk < 13) {
      int t = 2 * chunk + (q >> 1);
      int n = ((q & 1) << 3) + j;
      if (t <= 24 && t != 12) {
        int dy = t / 5 - 2, dx = t % 5 - 2;
        for (int o = 0; o < 16; ++o) {
          const float* wm = W00 + (o * 16 + m) * 9;
          const float* wn = W00 + (o * 16 + n) * 9;
          for (int ay = 0; ay < 3; ++ay) {
            int ay2 = ay + dy; if ((unsigned)ay2 > 2u) continue;
            for (int ax = 0; ax < 3; ++ax) {
              int ax2 = ax + dx; if ((unsigned)ax2 > 2u) continue;
              val += wm[ay * 3 + ax] * wn[ay2 * 3 + ax2];
            }
          }
        }
      }
    } else if (chunk < 22) {
      int tap = chunk - 13;
      int o = ((lane >> 4) << 3) + j;      // k = q*8+j
      val = W10[(o * 16 + m) * 9 + tap];
    } else {
      int py = chunk - 22;
      int k = ((lane >> 4) << 3) + j;
      int par = k >> 4, n = k & 15;
      for (int o = 0; o < 32; ++o) {
        const float* wn = W10 + (o * 16 + n) * 9;
        const float* wm = W10 + (o * 16 + m) * 9;
        for (int by = 0; by < 3; ++by) {
          if ((py == 0) ? (by != 1) : (by == 1)) continue;
          for (int bx = 0; bx < 3; ++bx) {
            if ((par == 0) ? (bx != 1) : (bx == 1)) continue;
            val -= wn[by * 3 + bx] * wm[by * 3 + bx];
          }
        }
      }
    }
    ((uint16_t*)(ws + AB0_OFF))[chunk * 512 + lane * 8 + j] = (uint16_t)bf16rne(val);
  } else if (e < 12288 + 10240) {
    int e2 = e - 12288;
    int chunk = e2 >> 10, r = e2 & 1023, h = r >> 9, le = r & 511;
    int lane = le >> 3, j = le & 7;
    int m = h * 16 + (lane & 15);
    int kk = ((lane >> 4) << 3) + j;      // k = q*8+j
    float val = 0.f;
    if (chunk < 9) {
      val = W11[(kk * 32 + m) * 9 + chunk];      // o = kk, tap = chunk
    } else if ((kk >> 4) == h) {
      int np = kk & 15;
      float s = 0.f;
      for (int o = 0; o < 32; ++o)
        for (int t = 0; t < 9; ++t)
          s += W11[(o * 32 + m) * 9 + t] * W11[(o * 32 + h * 16 + np) * 9 + t];
      val = -s;
    }
    ((uint16_t*)(ws + AB1_OFF))[(chunk * 2 + h) * 512 + lane * 8 + j] = (uint16_t)bf16rne(val);
  } else if (e < 12288 + 10240 + 28672) {
    int e3 = e - 22528;
    int chunk = e3 >> 9, le = e3 & 511;
    int lane = le >> 3, j = le & 7;
    int q = lane >> 4, m = lane & 15;
    int k = q * 8 + j;
    int part;
    float val = 0.f;
    if (chunk < 36) {
      int t = chunk >> 2, h = (chunk >> 1) & 1;
      part = chunk & 1;
      int o = h * 16 + m;
      val = W11[(o * 32 + k) * 9 + t];           // fwd: A[m=o][k=ich]
    } else {
      int c2 = chunk - 36;
      int c5 = c2 >> 2, h = (c2 >> 1) & 1;
      part = c2 & 1;
      int tap = 2 * c5 + (k >> 4);
      int o = h * 16 + m;
      if (tap <= 8) val = W10[(o * 16 + (k & 15)) * 9 + tap];
    }
    uint32_t hi = bf16rne(val);
    uint16_t outv;
    if (part == 0) outv = (uint16_t)hi;
    else outv = (uint16_t)bf16rne(val - __uint_as_float(hi << 16));
    ((uint16_t*)(ws + AB2_OFF))[chunk * 512 + lane * 8 + j] = outv;
  }
}

// ---------------------------------------------------------------------------
__global__ void sumsq_k(const float* __restrict__ src, int n, float* __restrict__ dst) {
  float s = 0.f;
  for (int i = blockIdx.x * blockDim.x + threadIdx.x; i < n; i += gridDim.x * blockDim.x) {
    float v = src[i];
    s += v * v;
  }
  #pragma unroll
  for (int off = 32; off > 0; off >>= 1) s += __shfl_down(s, off, 64);
  if ((threadIdx.x & 63) == 0) atomicAdd(dst, s);
}

// ---------------------------------------------------------------------------
// x1t[b][r][c][ch] = bf16(x1[b][ch][r][c])
__global__ __launch_bounds__(256) void x1t_k(const float* __restrict__ x1, char* __restrict__ ws) {
  __shared__ __align__(16) uint16_t tmp[128 * 32];
  int b = blockIdx.x >> 7, r = blockIdx.x & 127;
  int tid = threadIdx.x;
  for (int e = tid; e < 4096; e += 256) {
    int ch = e >> 7, c = e & 127;
    float v = x1[((size_t)(b * 32 + ch) * 128 + r) * 128 + c];
    tmp[c * 32 + ch] = (uint16_t)bf16rne(v);
  }
  __syncthreads();
  char* dst = ws + X1T_OFF + ((size_t)(b * 128 + r) * 128) * 64;
  for (int e = tid; e < 512; e += 256)
    *(short8*)(dst + e * 16) = *(const short8*)((const char*)tmp + e * 16);
}

// ---------------------------------------------------------------------------
// Y1 via MFMA: one block per (b, iy); 4 waves; 9 px-frags of 16 (130 used).
// LDS x0s: [ql 2][row 3][par 2][half-col 146][ch8] bf16 (col = 2h+p-3),
//          so stride-2 taps become unit-stride ds_read_b128.
// x1 B-frags: DIRECT global reads from x1t (frag-order layout, L1-resident).
// Weights from AB2 blob: hi+lo bf16 pairs -> only x carries bf16 rounding.
__global__ __launch_bounds__(256, 5) void y1m_k(const float* __restrict__ x0,
                                                char* __restrict__ ws) {
  __shared__ __align__(16) uint16_t x0s[2 * 3 * 2 * 146 * 8];   // 28,032 B
  int tid = threadIdx.x;
  int b = blockIdx.x / 130, iy = blockIdx.x % 130;

  { // zero-fill x0 tile (covers pads / OOB rows)
    uint4 z = make_uint4(0u, 0u, 0u, 0u);
    for (int e = tid; e < 1752; e += 256) ((uint4*)x0s)[e] = z;
  }
  __syncthreads();

  { // stage x0 rows 2iy-3..2iy-1 (fp32 -> bf16, even/odd col split)
    const float* x0b = x0 + (size_t)b * 1048576;
    for (int e = tid; e < 6144; e += 256) {
      int r = e >> 11;            // 0..2
      int ch0 = ((e >> 8) & 7) * 2;
      int c = e & 255;
      int gy = 2 * iy + r - 3;
      float v0 = 0.f, v1 = 0.f;
      if ((unsigned)gy < 256u) {
        const float* rp = x0b + (size_t)ch0 * 65536 + (size_t)gy * 256 + c;
        v0 = rp[0]; v1 = rp[65536];
      }
      int sc = c + 3, p = sc & 1, hc = sc >> 1;
      *(uint32_t*)((char*)x0s + ((((ch0 >> 3) * 3 + r) * 2 + p) * 146 + hc) * 16 + (ch0 & 7) * 2)
          = packbf(v0, v1);
    }
  }

  int lane = tid & 63, wv = tid >> 6;
  int nn = lane & 15, q = lane >> 4, qh = q >> 1, ql = q & 1;
  const char* ab2 = ws + AB2_OFF;
  const char* x1tb = ws + X1T_OFF;

  f32x4 a00 = {0.f,0.f,0.f,0.f}, a01 = {0.f,0.f,0.f,0.f};
  f32x4 a10 = {0.f,0.f,0.f,0.f}, a11 = {0.f,0.f,0.f,0.f};
  f32x4 a20 = {0.f,0.f,0.f,0.f}, a21 = {0.f,0.f,0.f,0.f};
  const short8 z8 = {0,0,0,0,0,0,0,0};

  // --- W11 fwd (s1,p2): 9 taps, K=32 in-ch; B-frags direct from x1t.
  //     Runs before the barrier: no LDS use, hides x0 ds_write drain. ---
  #pragma unroll
  for (int t = 0; t < 9; ++t) {
    const int ay = t / 3, ax = t % 3;
    const char* cb = ab2 + t * 4096 + lane * 16;
    short8 Ah0 = *(const short8*)(cb);
    short8 Al0 = *(const short8*)(cb + 1024);
    short8 Ah1 = *(const short8*)(cb + 2048);
    short8 Al1 = *(const short8*)(cb + 3072);
    int gy = iy + ay - 2;
    bool rowok = ((unsigned)gy < 128u);
    const char* rb = x1tb + ((size_t)(b * 128 + (rowok ? gy : 0))) * 8192 + q * 16;
    int c0 = (wv << 4) + nn + ax - 2;
    bool ok0 = rowok && ((unsigned)c0 < 128u);
    short8 B0 = *(const short8*)(rb + (size_t)(ok0 ? c0 : 0) * 64);
    if (!ok0) B0 = z8;
    int c1 = c0 + 64;
    bool ok1 = rowok && ((unsigned)c1 < 128u);
    short8 B1 = *(const short8*)(rb + (size_t)(ok1 ? c1 : 0) * 64);
    if (!ok1) B1 = z8;
    a00 = mfma16(Ah0, B0, a00); a00 = mfma16(Al0, B0, a00);
    a01 = mfma16(Ah1, B0, a01); a01 = mfma16(Al1, B0, a01);
    a10 = mfma16(Ah0, B1, a10); a10 = mfma16(Al0, B1, a10);
    a11 = mfma16(Ah1, B1, a11); a11 = mfma16(Al1, B1, a11);
    if (wv == 0) {
      int c2 = c0 + 128;
      bool ok2 = rowok && ((unsigned)c2 < 128u);
      short8 B2 = *(const short8*)(rb + (size_t)(ok2 ? c2 : 0) * 64);
      if (!ok2) B2 = z8;
      a20 = mfma16(Ah0, B2, a20); a20 = mfma16(Al0, B2, a20);
      a21 = mfma16(Ah1, B2, a21); a21 = mfma16(Al1, B2, a21);
    }
  }

  __syncthreads();   // x0s fully staged

  // --- W10 fwd (s2,p3): tap-pair chunks, k = qh*16 + ich ---
  #pragma unroll
  for (int c5 = 0; c5 < 5; ++c5) {
    const char* cb = ab2 + (36 + c5 * 4) * 1024 + lane * 16;
    short8 Ah0 = *(const short8*)(cb);
    short8 Al0 = *(const short8*)(cb + 1024);
    short8 Ah1 = *(const short8*)(cb + 2048);
    short8 Al1 = *(const short8*)(cb + 3072);
    int tl = 2 * c5 + qh; if (tl > 8) tl = 8;    // tap 9 zero-padded in A
    int by = tl / 3, bx = tl % 3;
    int p = bx & 1, hb = bx >> 1;
    const char* bb = (const char*)x0s + ((((ql * 3 + by) * 2 + p) * 146) + hb + nn) * 16 + wv * 256;
    short8 B0 = *(const short8*)(bb);
    short8 B1 = *(const short8*)(bb + 1024);
    a00 = mfma16(Ah0, B0, a00); a00 = mfma16(Al0, B0, a00);
    a01 = mfma16(Ah1, B0, a01); a01 = mfma16(Al1, B0, a01);
    a10 = mfma16(Ah0, B1, a10); a10 = mfma16(Al0, B1, a10);
    a11 = mfma16(Ah1, B1, a11); a11 = mfma16(Al1, B1, a11);
    if (wv == 0) {
      short8 B2 = *(const short8*)(bb + 2048);
      a20 = mfma16(Ah0, B2, a20); a20 = mfma16(Al0, B2, a20);
      a21 = mfma16(Ah1, B2, a21); a21 = mfma16(Al1, B2, a21);
    }
  }

  // --- store: Y1T[b][iy][ix][ch32] bf16, ix = f*16+nn, o = h*16+q*4+reg ---
  char* yp = ws + Y1T_OFF + (size_t)(b * 130 + iy) * Y1T_ROWB;
  auto st = [&](int f, f32x4 v0, f32x4 v1) {
    int ix = f * 16 + nn;
    if (ix < 130) {
      uint64_t lo = (uint64_t)packbf(v0[0], v0[1]) | ((uint64_t)packbf(v0[2], v0[3]) << 32);
      uint64_t hi = (uint64_t)packbf(v1[0], v1[1]) | ((uint64_t)packbf(v1[2], v1[3]) << 32);
      *(uint64_t*)(yp + ix * 64 + q * 8) = lo;
      *(uint64_t*)(yp + ix * 64 + 32 + q * 8) = hi;
    }
  };
  st(wv, a00, a01);
  st(wv + 4, a10, a11);
  if (wv == 0) st(8, a20, a21);
}

// ---------------------------------------------------------------------------
// out0: one block per (b, jy, half); 4 waves x 2 px-frags = 128 px.
// LDS 29.6 KB -> 5 blocks/CU. x0 staged as one ds_write_b128 per lane-task
// (coalesced 256B global reads per instr, conflict-free LDS writes).
__global__ __launch_bounds__(256, 5) void out0_k(const float* __restrict__ x0,
                                                 const float* __restrict__ b0,
                                                 const float* __restrict__ gg,
                                                 const char* __restrict__ ws,
                                                 float* __restrict__ out) {
  // x0s: [oct 2][row 5][col 132][ch 8] bf16; col c <-> gx = jx_base + c - 2
  __shared__ __align__(16) uint16_t x0s[2 * 5 * 132 * 8];   // 21,120 B
  // y1s: [q 4][ry 2][col 66][ch 8] bf16; ry 0/1 <-> y1 rows uy+1/uy+2,
  //      col lc <-> y1 col jx_base/2 + lc
  __shared__ __align__(16) uint16_t y1s[4 * 2 * 66 * 8];    // 8,448 B
  int tid = threadIdx.x;
  int b = blockIdx.x >> 9, jy = (blockIdx.x >> 1) & 255;
  int jx_base = (blockIdx.x & 1) << 7;

  { // stage x0: one 16B ch-octet granule per task
    const float* x0b = x0 + (size_t)b * 1048576;
    for (int e = tid; e < 1320; e += 256) {
      int c = e % 132, rr = e / 132, r = rr % 5, oct = rr / 5;
      int gy = jy + r - 2, gx = jx_base + c - 2;
      uint32_t w0 = 0u, w1 = 0u, w2 = 0u, w3 = 0u;
      if ((unsigned)gy < 256u && (unsigned)gx < 256u) {
        const float* p = x0b + (size_t)(oct * 8) * 65536 + gy * 256 + gx;
        w0 = packbf(p[0],      p[65536]);
        w1 = packbf(p[131072], p[196608]);
        w2 = packbf(p[262144], p[327680]);
        w3 = packbf(p[393216], p[458752]);
      }
      *(uint4*)((char*)x0s + (size_t)e * 16) = make_uint4(w0, w1, w2, w3);
    }
  }
  { // stage y1 rows uy+1, uy+2 (bf16 copy into q-planes)
    const char* y1tb = ws + Y1T_OFF;
    int uy = jy >> 1, c0 = jx_base >> 1;
    for (int e = tid; e < 528; e += 256) {
      int qq = e & 3, t = e >> 2, lc = t % 66, ry = t / 66;
      short8 v = *(const short8*)(y1tb +
          ((size_t)(b * 130 + uy + 1 + ry) * 132 + c0 + lc) * 64 + qq * 16);
      *(short8*)((char*)y1s + ((size_t)(qq * 2 + ry) * 66 + lc) * 16) = v;
    }
  }
  __syncthreads();

  int lane = tid & 63, wv = tid >> 6;
  int nn = lane & 15, q = lane >> 4, qh = q >> 1, ql = q & 1;
  const char* ab0 = ws + AB0_OFF;
  f32x4 acc[2];
  #pragma unroll
  for (int i = 0; i < 2; ++i) { acc[i][0]=0.f; acc[i][1]=0.f; acc[i][2]=0.f; acc[i][3]=0.f; }

  const uint16_t* xsl = x0s + ql * 5280;   // oct plane (5*132*8)
  const uint16_t* ysl = y1s + q * 1056;    // q plane (2*66*8)
  int pxb = wv * 32 + nn;

  // --- G00 5x5 (center zeroed), tap-pair chunks ---
  #pragma unroll
  for (int c = 0; c < 13; ++c) {
    short8 A = *(const short8*)(ab0 + c * 1024 + lane * 16);
    const int tA = 2 * c;
    const int tB = (2 * c + 1 > 24) ? 24 : 2 * c + 1;
    const int offA = ((tA / 5) * 132 + (tA % 5)) * 8;
    const int offB = ((tB / 5) * 132 + (tB % 5)) * 8;
    int toff = qh ? offB : offA;
    const uint16_t* base = xsl + toff + pxb * 8;
    short8 B0 = *(const short8*)(base);
    short8 B1 = *(const short8*)(base + 128);
    acc[0] = mfma16(A, B0, acc[0]);
    acc[1] = mfma16(A, B1, acc[1]);
  }

  // --- T10^T(Y1): compact cols + parity masks; rows fixed by jy parity ---
  {
    const short8 z8 = {0,0,0,0,0,0,0,0};
    if ((jy & 1) == 0) {
      #pragma unroll
      for (int bx = 0; bx < 3; ++bx) {
        short8 A = *(const short8*)(ab0 + (16 + bx) * 1024 + lane * 16);
        bool keep = (((nn + 3 - bx) & 1) == 0);
        int cb = (nn + 3 - bx) >> 1;
        const uint16_t* base = ysl + (cb + wv * 16) * 8;   // ry = 0
        short8 B0 = *(const short8*)(base);
        short8 B1 = *(const short8*)(base + 64);
        if (!keep) { B0 = z8; B1 = z8; }
        acc[0] = mfma16(A, B0, acc[0]);
        acc[1] = mfma16(A, B1, acc[1]);
      }
    } else {
      #pragma unroll
      for (int s = 0; s < 2; ++s) {          // s=0: by=0 (ry=1); s=1: by=2 (ry=0)
        const int chunkb = s ? 19 : 13;
        const int rybase = s ? 0 : 1;
        #pragma unroll
        for (int bx = 0; bx < 3; ++bx) {
          short8 A = *(const short8*)(ab0 + (chunkb + bx) * 1024 + lane * 16);
          bool keep = (((nn + 3 - bx) & 1) == 0);
          int cb = (nn + 3 - bx) >> 1;
          const uint16_t* base = ysl + (rybase * 66 + cb + wv * 16) * 8;
          short8 B0 = *(const short8*)(base);
          short8 B1 = *(const short8*)(base + 64);
          if (!keep) { B0 = z8; B1 = z8; }
          acc[0] = mfma16(A, B0, acc[0]);
          acc[1] = mfma16(A, B1, acc[1]);
        }
      }
    }
  }

  // --- hollow center: -G10c[jy-parity][px-parity], column-parity masked ---
  {
    const short8 z8 = {0,0,0,0,0,0,0,0};
    short8 A = *(const short8*)(ab0 + (22 + (jy & 1)) * 1024 + lane * 16);
    const uint16_t* base = xsl + (2 * 132 + 2) * 8 + pxb * 8;
    short8 B0 = *(const short8*)(base);
    short8 B1 = *(const short8*)(base + 128);
    bool keep = ((nn & 1) == qh);     // k<16 rows multiply even px, k>=16 odd px
    if (!keep) { B0 = z8; B1 = z8; }
    acc[0] = mfma16(A, B0, acc[0]);
    acc[1] = mfma16(A, B1, acc[1]);
  }

  // --- epilogue: out = b0_hat*g0 - acc ---
  float rs0 = gg[0] / sqrtf(((const float*)(ws + SUM_OFF))[0]);
  #pragma unroll
  for (int i = 0; i < 2; ++i) {
    int px = jx_base + wv * 32 + i * 16 + nn;
    #pragma unroll
    for (int reg = 0; reg < 4; ++reg) {
      int m = q * 4 + reg;
      size_t boff = ((size_t)m * 256 + jy) * 256 + px;
      out[((size_t)(b * 16 + m) * 256 + jy) * 256 + px] = b0[boff] * rs0 - acc[i][reg];
    }
  }
}

// ---------------------------------------------------------------------------
// out1: one block per (b, jy); 4 waves x 2 px-frags = 128 px; M=32 (2 blocks).
__global__ __launch_bounds__(256) void out1_k(const float* __restrict__ b1,
                                              const float* __restrict__ gg,
                                              const char* __restrict__ ws,
                                              float* __restrict__ out) {
  __shared__ __align__(16) uint16_t ys[4 * 3 * 132 * 8];   // 25,344 B
  __shared__ __align__(16) uint16_t x1s[4 * 128 * 8];      // 8,192 B
  int tid = threadIdx.x;
  int b = blockIdx.x >> 7, jy = blockIdx.x & 127;
  const char* y1tb = ws + Y1T_OFF;
  const char* x1tb = ws + X1T_OFF;
  for (int e = tid; e < 1584; e += 256) {
    int row = e / 528, rr = e % 528, c = rr >> 2, qq = rr & 3;
    short8 v = *(const short8*)(y1tb + ((size_t)(b * 130 + jy + row) * 132 + c) * 64 + qq * 16);
    *(short8*)(ys + qq * 3168 + (row * 132 + c) * 8) = v;
  }
  for (int e = tid; e < 512; e += 256) {
    int c = e >> 2, qq = e & 3;
    short8 v = *(const short8*)(x1tb + ((size_t)(b * 128 + jy) * 128 + c) * 64 + qq * 16);
    *(short8*)(x1s + qq * 1024 + c * 8) = v;
  }
  __syncthreads();

  int lane = tid & 63, wv = tid >> 6;
  int nn = lane & 15, q = lane >> 4;
  const char* ab1 = ws + AB1_OFF;
  f32x4 acc[2][2];
  #pragma unroll
  for (int i = 0; i < 2; ++i)
    #pragma unroll
    for (int h = 0; h < 2; ++h) { acc[i][h][0]=0.f; acc[i][h][1]=0.f; acc[i][h][2]=0.f; acc[i][h][3]=0.f; }

  const uint16_t* ysl = ys + q * 3168;
  const uint16_t* xsl = x1s + q * 1024;
  int pxb = wv * 32 + nn;

  #pragma unroll
  for (int t = 0; t < 9; ++t) {
    const int ay = t / 3, ax = t % 3;
    short8 A0 = *(const short8*)(ab1 + (t * 2 + 0) * 1024 + lane * 16);
    short8 A1 = *(const short8*)(ab1 + (t * 2 + 1) * 1024 + lane * 16);
    const uint16_t* base = ysl + ((2 - ay) * 132 + (2 - ax) + pxb) * 8;
    short8 B0 = *(const short8*)(base);
    short8 B1 = *(const short8*)(base + 128);
    acc[0][0] = mfma16(A0, B0, acc[0][0]);
    acc[0][1] = mfma16(A1, B0, acc[0][1]);
    acc[1][0] = mfma16(A0, B1, acc[1][0]);
    acc[1][1] = mfma16(A1, B1, acc[1][1]);
  }
  { // -sub1 blockdiag * x1
    short8 A0 = *(const short8*)(ab1 + 18 * 1024 + lane * 16);
    short8 A1 = *(const short8*)(ab1 + 19 * 1024 + lane * 16);
    const uint16_t* base = xsl + pxb * 8;
    short8 B0 = *(const short8*)(base);
    short8 B1 = *(const short8*)(base + 128);
    acc[0][0] = mfma16(A0, B0, acc[0][0]);
    acc[0][1] = mfma16(A1, B0, acc[0][1]);
    acc[1][0] = mfma16(A0, B1, acc[1][0]);
    acc[1][1] = mfma16(A1, B1, acc[1][1]);
  }

  float rs1 = gg[1] / sqrtf(((const float*)(ws + SUM_OFF))[1]);
  #pragma unroll
  for (int i = 0; i < 2; ++i) {
    int px = wv * 32 + i * 16 + nn;
    #pragma unroll
    for (int h = 0; h < 2; ++h)
      #pragma unroll
      for (int reg = 0; reg < 4; ++reg) {
        int m = h * 16 + q * 4 + reg;
        size_t boff = ((size_t)m * 128 + jy) * 128 + px;
        out[16777216 + ((size_t)(b * 32 + m) * 128 + jy) * 128 + px] = b1[boff] * rs1 - acc[i][h][reg];
      }
  }
}

// ---------------------------------------------------------------------------
extern "C" void kernel_launch(void* const* d_in, const int* in_sizes, int n_in,
                              void* d_out, int out_size, void* d_ws, size_t ws_size,
                              hipStream_t stream) {
  const float* x0  = (const float*)d_in[0];
  const float* x1  = (const float*)d_in[1];
  const float* W00 = (const float*)d_in[2];
  const float* W10 = (const float*)d_in[3];
  const float* W11 = (const float*)d_in[4];
  const float* b0  = (const float*)d_in[5];
  const float* b1  = (const float*)d_in[6];
  const float* g   = (const float*)d_in[7];
  float* out = (float*)d_out;
  char* ws   = (char*)d_ws;

  blob_k<<<200, 256, 0, stream>>>(W00, W10, W11, ws);
  sumsq_k<<<512, 256, 0, stream>>>(b0, 16 * 256 * 256, (float*)(ws + SUM_OFF));
  sumsq_k<<<512, 256, 0, stream>>>(b1, 32 * 128 * 128, (float*)(ws + SUM_OFF) + 1);
  x1t_k<<<2048, 256, 0, stream>>>(x1, ws);
  y1m_k<<<16 * 130, 256, 0, stream>>>(x0, ws);
  out0_k<<<8192, 256, 0, stream>>>(x0, b0, g, ws, out);
  out1_k<<<2048, 256, 0, stream>>>(b1, g, ws, out);
}

// Round 6
// 371.507 us; speedup vs baseline: 1.8103x; 1.0573x over previous
//
#include <hip/hip_runtime.h>
#include <stdint.h>

// ---------------------------------------------------------------------------
// MultiMonotoneHollowConv, round 7: XCD-aware block swizzle (T1).
//   out0 = -( G00(5x5,center->-G10c[phase]) * x0  +  T10^T(Y1)  - b0^*g0 )
//   out1 = -( W11^T(3x3) * Y1  -  sub1_blockdiag * x1  - b1^*g1 )
//   Y1   = conv(x0,W10,s2,p3) + conv(x1,W11,s1,p2)   [MFMA bf16,
//          weights split hi+lo bf16 so only x carries bf16 rounding]
// Swizzle: consecutive (b,jy) blocks share 3-5 input halo rows; default
//   dispatch round-robins XCDs so halo re-fetches miss the per-XCD L2
//   (out0_k FETCH 212 MB vs ~90 ideal). Contiguous-chunk-per-XCD remap
//   makes jy-neighbors same-L2. Grids all %8==0 -> bijective.
// MFMA frag layouts (gfx950, HW-verified per guide):
//   A[m=lane&15][k=quad*8+j], B[k=quad*8+j][n=lane&15], D: row m=quad*4+reg,
//   col n=lane&15.  K-chunks use ch-octet LDS planes so each B-frag is one
//   conflict-free ds_read_b128.
// ---------------------------------------------------------------------------

using short8 = __attribute__((ext_vector_type(8))) short;
using f32x4  = __attribute__((ext_vector_type(4))) float;

#define B_ 16

// workspace byte offsets (total ~34.45 MB; must stay < ~35.1 MB proven safe)
static constexpr size_t Y1T_OFF  = 0;                        // [16][130][132][32] bf16
static constexpr size_t Y1T_ROWB = 132 * 64;                 // 8448 B per (b,iy) row
static constexpr size_t X1T_OFF  = (size_t)16 * 130 * 132 * 64;        // 17,571,840
static constexpr size_t AB0_OFF  = X1T_OFF + (size_t)16 * 128 * 128 * 64; // +16,777,216
static constexpr size_t AB1_OFF  = AB0_OFF + 24 * 1024;     // blob0: 24 chunks
static constexpr size_t SUM_OFF  = AB1_OFF + 20 * 1024;     // blob1: 10 chunks x 2
static constexpr size_t AB2_OFF  = SUM_OFF + 1024;          // y1 fwd weights: 56 chunks

__device__ __forceinline__ uint32_t bf16rne(float v) {
  uint32_t u = __float_as_uint(v);
  return (u + 0x7fffu + ((u >> 16) & 1u)) >> 16;
}
__device__ __forceinline__ uint32_t packbf(float lo, float hi) {
  return bf16rne(lo) | (bf16rne(hi) << 16);
}
__device__ __forceinline__ f32x4 mfma16(short8 a, short8 b, f32x4 c) {
  return __builtin_amdgcn_mfma_f32_16x16x32_bf16(a, b, c, 0, 0, 0);
}
// XCD-aware swizzle: nblk % 8 == 0; each XCD gets a contiguous chunk.
__device__ __forceinline__ int xcd_swz(int bid, int chunk) {
  return (bid & 7) * chunk + (bid >> 3);
}

// ---------------------------------------------------------------------------
// Weight blobs in exact A-fragment order (bf16), plus zero the norm sums.
// blob0 (out0): [0..12] G00 tap-pairs (k=tap_sub*16+ch), center tap zeroed;
//               [13..21] W10t taps (k=o);  [22,23] -G10c parity chunks (py=0,1;
//               k<16 even-px rows, k>=16 odd-px rows).
// blob1 (out1): [t=0..8][h=0,1] W11 taps (k=o, m=h*16+..); [9][h] -sub1 blockdiag.
// blob2 (y1 fwd): [t 0..8][h][part hi/lo] W11 fwd (k=in ch, m=out ch h*16+..)
//                 then [c5 0..4][h][part] W10 fwd tap-pairs (k=qh*16+ich,
//                 tap = 2*c5+qh, tap 9 zero-padded).
__global__ void blob_k(const float* __restrict__ W00, const float* __restrict__ W10,
                       const float* __restrict__ W11, char* __restrict__ ws) {
  int e = blockIdx.x * 256 + threadIdx.x;
  if (e < 2) ((float*)(ws + SUM_OFF))[e] = 0.f;
  if (e < 12288) {
    int chunk = e >> 9, le = e & 511, lane = le >> 3, j = le & 7;
    int q = lane >> 4, m = lane & 15;
    float val = 0.f;
    if (chunk < 13) {
      int t = 2 * chunk + (q >> 1);
      int n = ((q & 1) << 3) + j;
      if (t <= 24 && t != 12) {
        int dy = t / 5 - 2, dx = t % 5 - 2;
        for (int o = 0; o < 16; ++o) {
          const float* wm = W00 + (o * 16 + m) * 9;
          const float* wn = W00 + (o * 16 + n) * 9;
          for (int ay = 0; ay < 3; ++ay) {
            int ay2 = ay + dy; if ((unsigned)ay2 > 2u) continue;
            for (int ax = 0; ax < 3; ++ax) {
              int ax2 = ax + dx; if ((unsigned)ax2 > 2u) continue;
              val += wm[ay * 3 + ax] * wn[ay2 * 3 + ax2];
            }
          }
        }
      }
    } else if (chunk < 22) {
      int tap = chunk - 13;
      int o = ((lane >> 4) << 3) + j;      // k = q*8+j
      val = W10[(o * 16 + m) * 9 + tap];
    } else {
      int py = chunk - 22;
      int k = ((lane >> 4) << 3) + j;
      int par = k >> 4, n = k & 15;
      for (int o = 0; o < 32; ++o) {
        const float* wn = W10 + (o * 16 + n) * 9;
        const float* wm = W10 + (o * 16 + m) * 9;
        for (int by = 0; by < 3; ++by) {
          if ((py == 0) ? (by != 1) : (by == 1)) continue;
          for (int bx = 0; bx < 3; ++bx) {
            if ((par == 0) ? (bx != 1) : (bx == 1)) continue;
            val -= wn[by * 3 + bx] * wm[by * 3 + bx];
          }
        }
      }
    }
    ((uint16_t*)(ws + AB0_OFF))[chunk * 512 + lane * 8 + j] = (uint16_t)bf16rne(val);
  } else if (e < 12288 + 10240) {
    int e2 = e - 12288;
    int chunk = e2 >> 10, r = e2 & 1023, h = r >> 9, le = r & 511;
    int lane = le >> 3, j = le & 7;
    int m = h * 16 + (lane & 15);
    int kk = ((lane >> 4) << 3) + j;      // k = q*8+j
    float val = 0.f;
    if (chunk < 9) {
      val = W11[(kk * 32 + m) * 9 + chunk];      // o = kk, tap = chunk
    } else if ((kk >> 4) == h) {
      int np = kk & 15;
      float s = 0.f;
      for (int o = 0; o < 32; ++o)
        for (int t = 0; t < 9; ++t)
          s += W11[(o * 32 + m) * 9 + t] * W11[(o * 32 + h * 16 + np) * 9 + t];
      val = -s;
    }
    ((uint16_t*)(ws + AB1_OFF))[(chunk * 2 + h) * 512 + lane * 8 + j] = (uint16_t)bf16rne(val);
  } else if (e < 12288 + 10240 + 28672) {
    int e3 = e - 22528;
    int chunk = e3 >> 9, le = e3 & 511;
    int lane = le >> 3, j = le & 7;
    int q = lane >> 4, m = lane & 15;
    int k = q * 8 + j;
    int part;
    float val = 0.f;
    if (chunk < 36) {
      int t = chunk >> 2, h = (chunk >> 1) & 1;
      part = chunk & 1;
      int o = h * 16 + m;
      val = W11[(o * 32 + k) * 9 + t];           // fwd: A[m=o][k=ich]
    } else {
      int c2 = chunk - 36;
      int c5 = c2 >> 2, h = (c2 >> 1) & 1;
      part = c2 & 1;
      int tap = 2 * c5 + (k >> 4);
      int o = h * 16 + m;
      if (tap <= 8) val = W10[(o * 16 + (k & 15)) * 9 + tap];
    }
    uint32_t hi = bf16rne(val);
    uint16_t outv;
    if (part == 0) outv = (uint16_t)hi;
    else outv = (uint16_t)bf16rne(val - __uint_as_float(hi << 16));
    ((uint16_t*)(ws + AB2_OFF))[chunk * 512 + lane * 8 + j] = outv;
  }
}

// ---------------------------------------------------------------------------
__global__ void sumsq_k(const float* __restrict__ src, int n, float* __restrict__ dst) {
  float s = 0.f;
  for (int i = blockIdx.x * blockDim.x + threadIdx.x; i < n; i += gridDim.x * blockDim.x) {
    float v = src[i];
    s += v * v;
  }
  #pragma unroll
  for (int off = 32; off > 0; off >>= 1) s += __shfl_down(s, off, 64);
  if ((threadIdx.x & 63) == 0) atomicAdd(dst, s);
}

// ---------------------------------------------------------------------------
// x1t[b][r][c][ch] = bf16(x1[b][ch][r][c])
__global__ __launch_bounds__(256) void x1t_k(const float* __restrict__ x1, char* __restrict__ ws) {
  __shared__ __align__(16) uint16_t tmp[128 * 32];
  int b = blockIdx.x >> 7, r = blockIdx.x & 127;
  int tid = threadIdx.x;
  for (int e = tid; e < 4096; e += 256) {
    int ch = e >> 7, c = e & 127;
    float v = x1[((size_t)(b * 32 + ch) * 128 + r) * 128 + c];
    tmp[c * 32 + ch] = (uint16_t)bf16rne(v);
  }
  __syncthreads();
  char* dst = ws + X1T_OFF + ((size_t)(b * 128 + r) * 128) * 64;
  for (int e = tid; e < 512; e += 256)
    *(short8*)(dst + e * 16) = *(const short8*)((const char*)tmp + e * 16);
}

// ---------------------------------------------------------------------------
// Y1 via MFMA: one block per (b, iy); 4 waves; 9 px-frags of 16 (130 used).
// LDS x0s: [ql 2][row 3][par 2][half-col 146][ch8] bf16 (col = 2h+p-3),
//          so stride-2 taps become unit-stride ds_read_b128.
// x1 B-frags: DIRECT global reads from x1t (frag-order layout, L1-resident).
// Weights from AB2 blob: hi+lo bf16 pairs -> only x carries bf16 rounding.
__global__ __launch_bounds__(256, 5) void y1m_k(const float* __restrict__ x0,
                                                char* __restrict__ ws) {
  __shared__ __align__(16) uint16_t x0s[2 * 3 * 2 * 146 * 8];   // 28,032 B
  int tid = threadIdx.x;
  int bid = xcd_swz(blockIdx.x, 260);          // 2080 blocks
  int b = bid / 130, iy = bid % 130;

  { // zero-fill x0 tile (covers pads / OOB rows)
    uint4 z = make_uint4(0u, 0u, 0u, 0u);
    for (int e = tid; e < 1752; e += 256) ((uint4*)x0s)[e] = z;
  }
  __syncthreads();

  { // stage x0 rows 2iy-3..2iy-1 (fp32 -> bf16, even/odd col split)
    const float* x0b = x0 + (size_t)b * 1048576;
    for (int e = tid; e < 6144; e += 256) {
      int r = e >> 11;            // 0..2
      int ch0 = ((e >> 8) & 7) * 2;
      int c = e & 255;
      int gy = 2 * iy + r - 3;
      float v0 = 0.f, v1 = 0.f;
      if ((unsigned)gy < 256u) {
        const float* rp = x0b + (size_t)ch0 * 65536 + (size_t)gy * 256 + c;
        v0 = rp[0]; v1 = rp[65536];
      }
      int sc = c + 3, p = sc & 1, hc = sc >> 1;
      *(uint32_t*)((char*)x0s + ((((ch0 >> 3) * 3 + r) * 2 + p) * 146 + hc) * 16 + (ch0 & 7) * 2)
          = packbf(v0, v1);
    }
  }

  int lane = tid & 63, wv = tid >> 6;
  int nn = lane & 15, q = lane >> 4, qh = q >> 1, ql = q & 1;
  const char* ab2 = ws + AB2_OFF;
  const char* x1tb = ws + X1T_OFF;

  f32x4 a00 = {0.f,0.f,0.f,0.f}, a01 = {0.f,0.f,0.f,0.f};
  f32x4 a10 = {0.f,0.f,0.f,0.f}, a11 = {0.f,0.f,0.f,0.f};
  f32x4 a20 = {0.f,0.f,0.f,0.f}, a21 = {0.f,0.f,0.f,0.f};
  const short8 z8 = {0,0,0,0,0,0,0,0};

  // --- W11 fwd (s1,p2): 9 taps, K=32 in-ch; B-frags direct from x1t.
  //     Runs before the barrier: no LDS use, hides x0 ds_write drain. ---
  #pragma unroll
  for (int t = 0; t < 9; ++t) {
    const int ay = t / 3, ax = t % 3;
    const char* cb = ab2 + t * 4096 + lane * 16;
    short8 Ah0 = *(const short8*)(cb);
    short8 Al0 = *(const short8*)(cb + 1024);
    short8 Ah1 = *(const short8*)(cb + 2048);
    short8 Al1 = *(const short8*)(cb + 3072);
    int gy = iy + ay - 2;
    bool rowok = ((unsigned)gy < 128u);
    const char* rb = x1tb + ((size_t)(b * 128 + (rowok ? gy : 0))) * 8192 + q * 16;
    int c0 = (wv << 4) + nn + ax - 2;
    bool ok0 = rowok && ((unsigned)c0 < 128u);
    short8 B0 = *(const short8*)(rb + (size_t)(ok0 ? c0 : 0) * 64);
    if (!ok0) B0 = z8;
    int c1 = c0 + 64;
    bool ok1 = rowok && ((unsigned)c1 < 128u);
    short8 B1 = *(const short8*)(rb + (size_t)(ok1 ? c1 : 0) * 64);
    if (!ok1) B1 = z8;
    a00 = mfma16(Ah0, B0, a00); a00 = mfma16(Al0, B0, a00);
    a01 = mfma16(Ah1, B0, a01); a01 = mfma16(Al1, B0, a01);
    a10 = mfma16(Ah0, B1, a10); a10 = mfma16(Al0, B1, a10);
    a11 = mfma16(Ah1, B1, a11); a11 = mfma16(Al1, B1, a11);
    if (wv == 0) {
      int c2 = c0 + 128;
      bool ok2 = rowok && ((unsigned)c2 < 128u);
      short8 B2 = *(const short8*)(rb + (size_t)(ok2 ? c2 : 0) * 64);
      if (!ok2) B2 = z8;
      a20 = mfma16(Ah0, B2, a20); a20 = mfma16(Al0, B2, a20);
      a21 = mfma16(Ah1, B2, a21); a21 = mfma16(Al1, B2, a21);
    }
  }

  __syncthreads();   // x0s fully staged

  // --- W10 fwd (s2,p3): tap-pair chunks, k = qh*16 + ich ---
  #pragma unroll
  for (int c5 = 0; c5 < 5; ++c5) {
    const char* cb = ab2 + (36 + c5 * 4) * 1024 + lane * 16;
    short8 Ah0 = *(const short8*)(cb);
    short8 Al0 = *(const short8*)(cb + 1024);
    short8 Ah1 = *(const short8*)(cb + 2048);
    short8 Al1 = *(const short8*)(cb + 3072);
    int tl = 2 * c5 + qh; if (tl > 8) tl = 8;    // tap 9 zero-padded in A
    int by = tl / 3, bx = tl % 3;
    int p = bx & 1, hb = bx >> 1;
    const char* bb = (const char*)x0s + ((((ql * 3 + by) * 2 + p) * 146) + hb + nn) * 16 + wv * 256;
    short8 B0 = *(const short8*)(bb);
    short8 B1 = *(const short8*)(bb + 1024);
    a00 = mfma16(Ah0, B0, a00); a00 = mfma16(Al0, B0, a00);
    a01 = mfma16(Ah1, B0, a01); a01 = mfma16(Al1, B0, a01);
    a10 = mfma16(Ah0, B1, a10); a10 = mfma16(Al0, B1, a10);
    a11 = mfma16(Ah1, B1, a11); a11 = mfma16(Al1, B1, a11);
    if (wv == 0) {
      short8 B2 = *(const short8*)(bb + 2048);
      a20 = mfma16(Ah0, B2, a20); a20 = mfma16(Al0, B2, a20);
      a21 = mfma16(Ah1, B2, a21); a21 = mfma16(Al1, B2, a21);
    }
  }

  // --- store: Y1T[b][iy][ix][ch32] bf16, ix = f*16+nn, o = h*16+q*4+reg ---
  char* yp = ws + Y1T_OFF + (size_t)(b * 130 + iy) * Y1T_ROWB;
  auto st = [&](int f, f32x4 v0, f32x4 v1) {
    int ix = f * 16 + nn;
    if (ix < 130) {
      uint64_t lo = (uint64_t)packbf(v0[0], v0[1]) | ((uint64_t)packbf(v0[2], v0[3]) << 32);
      uint64_t hi = (uint64_t)packbf(v1[0], v1[1]) | ((uint64_t)packbf(v1[2], v1[3]) << 32);
      *(uint64_t*)(yp + ix * 64 + q * 8) = lo;
      *(uint64_t*)(yp + ix * 64 + 32 + q * 8) = hi;
    }
  };
  st(wv, a00, a01);
  st(wv + 4, a10, a11);
  if (wv == 0) st(8, a20, a21);
}

// ---------------------------------------------------------------------------
// out0: one block per (b, jy, half); 4 waves x 2 px-frags = 128 px.
// LDS 29.6 KB -> 5 blocks/CU. x0 staged as one ds_write_b128 per lane-task
// (coalesced 256B global reads per instr, conflict-free LDS writes).
__global__ __launch_bounds__(256, 5) void out0_k(const float* __restrict__ x0,
                                                 const float* __restrict__ b0,
                                                 const float* __restrict__ gg,
                                                 const char* __restrict__ ws,
                                                 float* __restrict__ out) {
  // x0s: [oct 2][row 5][col 132][ch 8] bf16; col c <-> gx = jx_base + c - 2
  __shared__ __align__(16) uint16_t x0s[2 * 5 * 132 * 8];   // 21,120 B
  // y1s: [q 4][ry 2][col 66][ch 8] bf16; ry 0/1 <-> y1 rows uy+1/uy+2,
  //      col lc <-> y1 col jx_base/2 + lc
  __shared__ __align__(16) uint16_t y1s[4 * 2 * 66 * 8];    // 8,448 B
  int tid = threadIdx.x;
  int bid = xcd_swz(blockIdx.x, 1024);         // 8192 blocks
  int b = bid >> 9, jy = (bid >> 1) & 255;
  int jx_base = (bid & 1) << 7;

  { // stage x0: one 16B ch-octet granule per task
    const float* x0b = x0 + (size_t)b * 1048576;
    for (int e = tid; e < 1320; e += 256) {
      int c = e % 132, rr = e / 132, r = rr % 5, oct = rr / 5;
      int gy = jy + r - 2, gx = jx_base + c - 2;
      uint32_t w0 = 0u, w1 = 0u, w2 = 0u, w3 = 0u;
      if ((unsigned)gy < 256u && (unsigned)gx < 256u) {
        const float* p = x0b + (size_t)(oct * 8) * 65536 + gy * 256 + gx;
        w0 = packbf(p[0],      p[65536]);
        w1 = packbf(p[131072], p[196608]);
        w2 = packbf(p[262144], p[327680]);
        w3 = packbf(p[393216], p[458752]);
      }
      *(uint4*)((char*)x0s + (size_t)e * 16) = make_uint4(w0, w1, w2, w3);
    }
  }
  { // stage y1 rows uy+1, uy+2 (bf16 copy into q-planes)
    const char* y1tb = ws + Y1T_OFF;
    int uy = jy >> 1, c0 = jx_base >> 1;
    for (int e = tid; e < 528; e += 256) {
      int qq = e & 3, t = e >> 2, lc = t % 66, ry = t / 66;
      short8 v = *(const short8*)(y1tb +
          ((size_t)(b * 130 + uy + 1 + ry) * 132 + c0 + lc) * 64 + qq * 16);
      *(short8*)((char*)y1s + ((size_t)(qq * 2 + ry) * 66 + lc) * 16) = v;
    }
  }
  __syncthreads();

  int lane = tid & 63, wv = tid >> 6;
  int nn = lane & 15, q = lane >> 4, qh = q >> 1, ql = q & 1;
  const char* ab0 = ws + AB0_OFF;
  f32x4 acc[2];
  #pragma unroll
  for (int i = 0; i < 2; ++i) { acc[i][0]=0.f; acc[i][1]=0.f; acc[i][2]=0.f; acc[i][3]=0.f; }

  const uint16_t* xsl = x0s + ql * 5280;   // oct plane (5*132*8)
  const uint16_t* ysl = y1s + q * 1056;    // q plane (2*66*8)
  int pxb = wv * 32 + nn;

  // --- G00 5x5 (center zeroed), tap-pair chunks ---
  #pragma unroll
  for (int c = 0; c < 13; ++c) {
    short8 A = *(const short8*)(ab0 + c * 1024 + lane * 16);
    const int tA = 2 * c;
    const int tB = (2 * c + 1 > 24) ? 24 : 2 * c + 1;
    const int offA = ((tA / 5) * 132 + (tA % 5)) * 8;
    const int offB = ((tB / 5) * 132 + (tB % 5)) * 8;
    int toff = qh ? offB : offA;
    const uint16_t* base = xsl + toff + pxb * 8;
    short8 B0 = *(const short8*)(base);
    short8 B1 = *(const short8*)(base + 128);
    acc[0] = mfma16(A, B0, acc[0]);
    acc[1] = mfma16(A, B1, acc[1]);
  }

  // --- T10^T(Y1): compact cols + parity masks; rows fixed by jy parity ---
  {
    const short8 z8 = {0,0,0,0,0,0,0,0};
    if ((jy & 1) == 0) {
      #pragma unroll
      for (int bx = 0; bx < 3; ++bx) {
        short8 A = *(const short8*)(ab0 + (16 + bx) * 1024 + lane * 16);
        bool keep = (((nn + 3 - bx) & 1) == 0);
        int cb = (nn + 3 - bx) >> 1;
        const uint16_t* base = ysl + (cb + wv * 16) * 8;   // ry = 0
        short8 B0 = *(const short8*)(base);
        short8 B1 = *(const short8*)(base + 64);
        if (!keep) { B0 = z8; B1 = z8; }
        acc[0] = mfma16(A, B0, acc[0]);
        acc[1] = mfma16(A, B1, acc[1]);
      }
    } else {
      #pragma unroll
      for (int s = 0; s < 2; ++s) {          // s=0: by=0 (ry=1); s=1: by=2 (ry=0)
        const int chunkb = s ? 19 : 13;
        const int rybase = s ? 0 : 1;
        #pragma unroll
        for (int bx = 0; bx < 3; ++bx) {
          short8 A = *(const short8*)(ab0 + (chunkb + bx) * 1024 + lane * 16);
          bool keep = (((nn + 3 - bx) & 1) == 0);
          int cb = (nn + 3 - bx) >> 1;
          const uint16_t* base = ysl + (rybase * 66 + cb + wv * 16) * 8;
          short8 B0 = *(const short8*)(base);
          short8 B1 = *(const short8*)(base + 64);
          if (!keep) { B0 = z8; B1 = z8; }
          acc[0] = mfma16(A, B0, acc[0]);
          acc[1] = mfma16(A, B1, acc[1]);
        }
      }
    }
  }

  // --- hollow center: -G10c[jy-parity][px-parity], column-parity masked ---
  {
    const short8 z8 = {0,0,0,0,0,0,0,0};
    short8 A = *(const short8*)(ab0 + (22 + (jy & 1)) * 1024 + lane * 16);
    const uint16_t* base = xsl + (2 * 132 + 2) * 8 + pxb * 8;
    short8 B0 = *(const short8*)(base);
    short8 B1 = *(const short8*)(base + 128);
    bool keep = ((nn & 1) == qh);     // k<16 rows multiply even px, k>=16 odd px
    if (!keep) { B0 = z8; B1 = z8; }
    acc[0] = mfma16(A, B0, acc[0]);
    acc[1] = mfma16(A, B1, acc[1]);
  }

  // --- epilogue: out = b0_hat*g0 - acc ---
  float rs0 = gg[0] / sqrtf(((const float*)(ws + SUM_OFF))[0]);
  #pragma unroll
  for (int i = 0; i < 2; ++i) {
    int px = jx_base + wv * 32 + i * 16 + nn;
    #pragma unroll
    for (int reg = 0; reg < 4; ++reg) {
      int m = q * 4 + reg;
      size_t boff = ((size_t)m * 256 + jy) * 256 + px;
      out[((size_t)(b * 16 + m) * 256 + jy) * 256 + px] = b0[boff] * rs0 - acc[i][reg];
    }
  }
}

// ---------------------------------------------------------------------------
// out1: one block per (b, jy); 4 waves x 2 px-frags = 128 px; M=32 (2 blocks).
__global__ __launch_bounds__(256) void out1_k(const float* __restrict__ b1,
                                              const float* __restrict__ gg,
                                              const char* __restrict__ ws,
                                              float* __restrict__ out) {
  __shared__ __align__(16) uint16_t ys[4 * 3 * 132 * 8];   // 25,344 B
  __shared__ __align__(16) uint16_t x1s[4 * 128 * 8];      // 8,192 B
  int tid = threadIdx.x;
  int bid = xcd_swz(blockIdx.x, 256);          // 2048 blocks
  int b = bid >> 7, jy = bid & 127;
  const char* y1tb = ws + Y1T_OFF;
  const char* x1tb = ws + X1T_OFF;
  for (int e = tid; e < 1584; e += 256) {
    int row = e / 528, rr = e % 528, c = rr >> 2, qq = rr & 3;
    short8 v = *(const short8*)(y1tb + ((size_t)(b * 130 + jy + row) * 132 + c) * 64 + qq * 16);
    *(short8*)(ys + qq * 3168 + (row * 132 + c) * 8) = v;
  }
  for (int e = tid; e < 512; e += 256) {
    int c = e >> 2, qq = e & 3;
    short8 v = *(const short8*)(x1tb + ((size_t)(b * 128 + jy) * 128 + c) * 64 + qq * 16);
    *(short8*)(x1s + qq * 1024 + c * 8) = v;
  }
  __syncthreads();

  int lane = tid & 63, wv = tid >> 6;
  int nn = lane & 15, q = lane >> 4;
  const char* ab1 = ws + AB1_OFF;
  f32x4 acc[2][2];
  #pragma unroll
  for (int i = 0; i < 2; ++i)
    #pragma unroll
    for (int h = 0; h < 2; ++h) { acc[i][h][0]=0.f; acc[i][h][1]=0.f; acc[i][h][2]=0.f; acc[i][h][3]=0.f; }

  const uint16_t* ysl = ys + q * 3168;
  const uint16_t* xsl = x1s + q * 1024;
  int pxb = wv * 32 + nn;

  #pragma unroll
  for (int t = 0; t < 9; ++t) {
    const int ay = t / 3, ax = t % 3;
    short8 A0 = *(const short8*)(ab1 + (t * 2 + 0) * 1024 + lane * 16);
    short8 A1 = *(const short8*)(ab1 + (t * 2 + 1) * 1024 + lane * 16);
    const uint16_t* base = ysl + ((2 - ay) * 132 + (2 - ax) + pxb) * 8;
    short8 B0 = *(const short8*)(base);
    short8 B1 = *(const short8*)(base + 128);
    acc[0][0] = mfma16(A0, B0, acc[0][0]);
    acc[0][1] = mfma16(A1, B0, acc[0][1]);
    acc[1][0] = mfma16(A0, B1, acc[1][0]);
    acc[1][1] = mfma16(A1, B1, acc[1][1]);
  }
  { // -sub1 blockdiag * x1
    short8 A0 = *(const short8*)(ab1 + 18 * 1024 + lane * 16);
    short8 A1 = *(const short8*)(ab1 + 19 * 1024 + lane * 16);
    const uint16_t* base = xsl + pxb * 8;
    short8 B0 = *(const short8*)(base);
    short8 B1 = *(const short8*)(base + 128);
    acc[0][0] = mfma16(A0, B0, acc[0][0]);
    acc[0][1] = mfma16(A1, B0, acc[0][1]);
    acc[1][0] = mfma16(A0, B1, acc[1][0]);
    acc[1][1] = mfma16(A1, B1, acc[1][1]);
  }

  float rs1 = gg[1] / sqrtf(((const float*)(ws + SUM_OFF))[1]);
  #pragma unroll
  for (int i = 0; i < 2; ++i) {
    int px = wv * 32 + i * 16 + nn;
    #pragma unroll
    for (int h = 0; h < 2; ++h)
      #pragma unroll
      for (int reg = 0; reg < 4; ++reg) {
        int m = h * 16 + q * 4 + reg;
        size_t boff = ((size_t)m * 128 + jy) * 128 + px;
        out[16777216 + ((size_t)(b * 32 + m) * 128 + jy) * 128 + px] = b1[boff] * rs1 - acc[i][h][reg];
      }
  }
}

// ---------------------------------------------------------------------------
extern "C" void kernel_launch(void* const* d_in, const int* in_sizes, int n_in,
                              void* d_out, int out_size, void* d_ws, size_t ws_size,
                              hipStream_t stream) {
  const float* x0  = (const float*)d_in[0];
  const float* x1  = (const float*)d_in[1];
  const float* W00 = (const float*)d_in[2];
  const float* W10 = (const float*)d_in[3];
  const float* W11 = (const float*)d_in[4];
  const float* b0  = (const float*)d_in[5];
  const float* b1  = (const float*)d_in[6];
  const float* g   = (const float*)d_in[7];
  float* out = (float*)d_out;
  char* ws   = (char*)d_ws;

  blob_k<<<200, 256, 0, stream>>>(W00, W10, W11, ws);
  sumsq_k<<<512, 256, 0, stream>>>(b0, 16 * 256 * 256, (float*)(ws + SUM_OFF));
  sumsq_k<<<512, 256, 0, stream>>>(b1, 32 * 128 * 128, (float*)(ws + SUM_OFF) + 1);
  x1t_k<<<2048, 256, 0, stream>>>(x1, ws);
  y1m_k<<<16 * 130, 256, 0, stream>>>(x0, ws);
  out0_k<<<8192, 256, 0, stream>>>(x0, b0, g, ws, out);
  out1_k<<<2048, 256, 0, stream>>>(b1, g, ws, out);
}

// Round 7
// 319.831 us; speedup vs baseline: 2.1027x; 1.1616x over previous
//
#include <hip/hip_runtime.h>
#include <stdint.h>

// ---------------------------------------------------------------------------
// MultiMonotoneHollowConv, round 8: launch-graph fusion 7 -> 3.
//   phase A prep_k : x1t transpose  |  weight blobs  |  bias sumsq partials
//   phase B y1m_k  : Y1 MFMA (+1 block reduces sumsq partials -> SUM)
//   phase C outs_k : out0 (LDS-staged)  |  out1 (de-staged, direct global)
// Rationale: per-iteration kernel sum ~225us vs 371us total -> ~145us of
//   inter-launch drain across 6 boundaries; dependency graph needs only 3.
// out1 de-stage: Y1T/X1T are stored in exact B-frag order; 33KB/block is
//   L1/L2-resident, so fragments read direct from global (round-5 pattern).
// MFMA frag layouts (gfx950, HW-verified per guide):
//   A[m=lane&15][k=quad*8+j], B[k=quad*8+j][n=lane&15], D: row m=quad*4+reg,
//   col n=lane&15.
// ---------------------------------------------------------------------------

using short8 = __attribute__((ext_vector_type(8))) short;
using f32x4  = __attribute__((ext_vector_type(4))) float;

#define B_ 16

// workspace byte offsets (total ~34.46 MB; must stay < ~35.1 MB proven safe)
static constexpr size_t Y1T_OFF  = 0;                        // [16][130][132][32] bf16
static constexpr size_t Y1T_ROWB = 132 * 64;                 // 8448 B per (b,iy) row
static constexpr size_t X1T_OFF  = (size_t)16 * 130 * 132 * 64;        // 17,571,840
static constexpr size_t AB0_OFF  = X1T_OFF + (size_t)16 * 128 * 128 * 64; // +16,777,216
static constexpr size_t AB1_OFF  = AB0_OFF + 24 * 1024;     // blob0: 24 chunks
static constexpr size_t SUM_OFF  = AB1_OFF + 20 * 1024;     // blob1: 10 chunks x 2
static constexpr size_t AB2_OFF  = SUM_OFF + 1024;          // y1 fwd weights: 56 chunks
static constexpr size_t PART_OFF = AB2_OFF + 56 * 1024;     // sumsq partials: 384 f32

__device__ __forceinline__ uint32_t bf16rne(float v) {
  uint32_t u = __float_as_uint(v);
  return (u + 0x7fffu + ((u >> 16) & 1u)) >> 16;
}
__device__ __forceinline__ uint32_t packbf(float lo, float hi) {
  return bf16rne(lo) | (bf16rne(hi) << 16);
}
__device__ __forceinline__ f32x4 mfma16(short8 a, short8 b, f32x4 c) {
  return __builtin_amdgcn_mfma_f32_16x16x32_bf16(a, b, c, 0, 0, 0);
}
// XCD-aware swizzle: nblk % 8 == 0; each XCD gets a contiguous chunk.
__device__ __forceinline__ int xcd_swz(int bid, int chunk) {
  return (bid & 7) * chunk + (bid >> 3);
}

// ---------------------------------------------------------------------------
// prep_k: raw [0,2048) x1t | [2048,2248) blob | [2248,2312) sumsq b0 (64 blk,
// per-wave partial slots 0..255) | [2312,2344) sumsq b1 (slots 256..383).
// All writes to disjoint regions -> no intra-kernel cross-block hazards.
__global__ __launch_bounds__(256) void prep_k(const float* __restrict__ x1,
                                              const float* __restrict__ W00,
                                              const float* __restrict__ W10,
                                              const float* __restrict__ W11,
                                              const float* __restrict__ b0,
                                              const float* __restrict__ b1,
                                              char* __restrict__ ws) {
  __shared__ __align__(16) uint16_t tmp[128 * 32];   // x1t path only (8 KB)
  int raw = blockIdx.x, tid = threadIdx.x;

  if (raw < 2048) {
    // --- x1t[b][r][c][ch] = bf16(x1[b][ch][r][c]) ---
    int b = raw >> 7, r = raw & 127;
    for (int e = tid; e < 4096; e += 256) {
      int ch = e >> 7, c = e & 127;
      float v = x1[((size_t)(b * 32 + ch) * 128 + r) * 128 + c];
      tmp[c * 32 + ch] = (uint16_t)bf16rne(v);
    }
    __syncthreads();
    char* dst = ws + X1T_OFF + ((size_t)(b * 128 + r) * 128) * 64;
    for (int e = tid; e < 512; e += 256)
      *(short8*)(dst + e * 16) = *(const short8*)((const char*)tmp + e * 16);
    return;
  }

  if (raw < 2248) {
    // --- weight blobs (exact A-fragment order, bf16) ---
    int e = (raw - 2048) * 256 + tid;
    if (e < 12288) {
      int chunk = e >> 9, le = e & 511, lane = le >> 3, j = le & 7;
      int q = lane >> 4, m = lane & 15;
      float val = 0.f;
      if (chunk < 13) {
        int t = 2 * chunk + (q >> 1);
        int n = ((q & 1) << 3) + j;
        if (t <= 24 && t != 12) {
          int dy = t / 5 - 2, dx = t % 5 - 2;
          for (int o = 0; o < 16; ++o) {
            const float* wm = W00 + (o * 16 + m) * 9;
            const float* wn = W00 + (o * 16 + n) * 9;
            for (int ay = 0; ay < 3; ++ay) {
              int ay2 = ay + dy; if ((unsigned)ay2 > 2u) continue;
              for (int ax = 0; ax < 3; ++ax) {
                int ax2 = ax + dx; if ((unsigned)ax2 > 2u) continue;
                val += wm[ay * 3 + ax] * wn[ay2 * 3 + ax2];
              }
            }
          }
        }
      } else if (chunk < 22) {
        int tap = chunk - 13;
        int o = ((lane >> 4) << 3) + j;      // k = q*8+j
        val = W10[(o * 16 + m) * 9 + tap];
      } else {
        int py = chunk - 22;
        int k = ((lane >> 4) << 3) + j;
        int par = k >> 4, n = k & 15;
        for (int o = 0; o < 32; ++o) {
          const float* wn = W10 + (o * 16 + n) * 9;
          const float* wm = W10 + (o * 16 + m) * 9;
          for (int by = 0; by < 3; ++by) {
            if ((py == 0) ? (by != 1) : (by == 1)) continue;
            for (int bx = 0; bx < 3; ++bx) {
              if ((par == 0) ? (bx != 1) : (bx == 1)) continue;
              val -= wn[by * 3 + bx] * wm[by * 3 + bx];
            }
          }
        }
      }
      ((uint16_t*)(ws + AB0_OFF))[chunk * 512 + lane * 8 + j] = (uint16_t)bf16rne(val);
    } else if (e < 12288 + 10240) {
      int e2 = e - 12288;
      int chunk = e2 >> 10, r = e2 & 1023, h = r >> 9, le = r & 511;
      int lane = le >> 3, j = le & 7;
      int m = h * 16 + (lane & 15);
      int kk = ((lane >> 4) << 3) + j;      // k = q*8+j
      float val = 0.f;
      if (chunk < 9) {
        val = W11[(kk * 32 + m) * 9 + chunk];      // o = kk, tap = chunk
      } else if ((kk >> 4) == h) {
        int np = kk & 15;
        float s = 0.f;
        for (int o = 0; o < 32; ++o)
          for (int t = 0; t < 9; ++t)
            s += W11[(o * 32 + m) * 9 + t] * W11[(o * 32 + h * 16 + np) * 9 + t];
        val = -s;
      }
      ((uint16_t*)(ws + AB1_OFF))[(chunk * 2 + h) * 512 + lane * 8 + j] = (uint16_t)bf16rne(val);
    } else if (e < 12288 + 10240 + 28672) {
      int e3 = e - 22528;
      int chunk = e3 >> 9, le = e3 & 511;
      int lane = le >> 3, j = le & 7;
      int q = lane >> 4, m = lane & 15;
      int k = q * 8 + j;
      int part;
      float val = 0.f;
      if (chunk < 36) {
        int t = chunk >> 2, h = (chunk >> 1) & 1;
        part = chunk & 1;
        int o = h * 16 + m;
        val = W11[(o * 32 + k) * 9 + t];           // fwd: A[m=o][k=ich]
      } else {
        int c2 = chunk - 36;
        int c5 = c2 >> 2, h = (c2 >> 1) & 1;
        part = c2 & 1;
        int tap = 2 * c5 + (k >> 4);
        int o = h * 16 + m;
        if (tap <= 8) val = W10[(o * 16 + (k & 15)) * 9 + tap];
      }
      uint32_t hi = bf16rne(val);
      uint16_t outv;
      if (part == 0) outv = (uint16_t)hi;
      else outv = (uint16_t)bf16rne(val - __uint_as_float(hi << 16));
      ((uint16_t*)(ws + AB2_OFF))[chunk * 512 + lane * 8 + j] = outv;
    }
    return;
  }

  // --- sumsq partials (write-only slots, no init / no atomics) ---
  float* part = (float*)(ws + PART_OFF);
  if (raw < 2312) {
    int blk = raw - 2248;                  // 64 blocks over b0 (1,048,576)
    float s = 0.f;
    for (int i = blk * 256 + tid; i < 1048576; i += 64 * 256) {
      float v = b0[i]; s += v * v;
    }
    #pragma unroll
    for (int off = 32; off > 0; off >>= 1) s += __shfl_down(s, off, 64);
    if ((tid & 63) == 0) part[blk * 4 + (tid >> 6)] = s;
  } else {
    int blk = raw - 2312;                  // 32 blocks over b1 (524,288)
    float s = 0.f;
    for (int i = blk * 256 + tid; i < 524288; i += 32 * 256) {
      float v = b1[i]; s += v * v;
    }
    #pragma unroll
    for (int off = 32; off > 0; off >>= 1) s += __shfl_down(s, off, 64);
    if ((tid & 63) == 0) part[256 + blk * 4 + (tid >> 6)] = s;
  }
}

// ---------------------------------------------------------------------------
// Y1 via MFMA: one block per (b, iy); 4 waves; 9 px-frags of 16 (130 used).
// LDS x0s: [ql 2][row 3][par 2][half-col 146][ch8] bf16 (col = 2h+p-3).
// x1 B-frags: DIRECT global reads from x1t (frag-order layout, L1-resident).
// Grid 2088: raw 2080 reduces sumsq partials -> SUM; 2081..2087 exit.
__global__ __launch_bounds__(256, 5) void y1m_k(const float* __restrict__ x0,
                                                char* __restrict__ ws) {
  __shared__ __align__(16) uint16_t x0s[2 * 3 * 2 * 146 * 8];   // 28,032 B
  int tid = threadIdx.x;
  if (blockIdx.x >= 2080) {
    if (blockIdx.x == 2080) {
      int lane = tid & 63, wvv = tid >> 6;
      const float* part = (const float*)(ws + PART_OFF);
      if (wvv == 0) {
        float s = part[lane * 4] + part[lane * 4 + 1] + part[lane * 4 + 2] + part[lane * 4 + 3];
        #pragma unroll
        for (int off = 32; off > 0; off >>= 1) s += __shfl_down(s, off, 64);
        if (lane == 0) ((float*)(ws + SUM_OFF))[0] = s;
      } else if (wvv == 1) {
        float s = part[256 + lane * 2] + part[256 + lane * 2 + 1];
        #pragma unroll
        for (int off = 32; off > 0; off >>= 1) s += __shfl_down(s, off, 64);
        if (lane == 0) ((float*)(ws + SUM_OFF))[1] = s;
      }
    }
    return;
  }
  int bid = xcd_swz(blockIdx.x, 260);          // 2080 work blocks
  int b = bid / 130, iy = bid % 130;

  { // zero-fill x0 tile (covers pads / OOB rows)
    uint4 z = make_uint4(0u, 0u, 0u, 0u);
    for (int e = tid; e < 1752; e += 256) ((uint4*)x0s)[e] = z;
  }
  __syncthreads();

  { // stage x0 rows 2iy-3..2iy-1 (fp32 -> bf16, even/odd col split)
    const float* x0b = x0 + (size_t)b * 1048576;
    for (int e = tid; e < 6144; e += 256) {
      int r = e >> 11;            // 0..2
      int ch0 = ((e >> 8) & 7) * 2;
      int c = e & 255;
      int gy = 2 * iy + r - 3;
      float v0 = 0.f, v1 = 0.f;
      if ((unsigned)gy < 256u) {
        const float* rp = x0b + (size_t)ch0 * 65536 + (size_t)gy * 256 + c;
        v0 = rp[0]; v1 = rp[65536];
      }
      int sc = c + 3, p = sc & 1, hc = sc >> 1;
      *(uint32_t*)((char*)x0s + ((((ch0 >> 3) * 3 + r) * 2 + p) * 146 + hc) * 16 + (ch0 & 7) * 2)
          = packbf(v0, v1);
    }
  }

  int lane = tid & 63, wv = tid >> 6;
  int nn = lane & 15, q = lane >> 4, qh = q >> 1, ql = q & 1;
  const char* ab2 = ws + AB2_OFF;
  const char* x1tb = ws + X1T_OFF;

  f32x4 a00 = {0.f,0.f,0.f,0.f}, a01 = {0.f,0.f,0.f,0.f};
  f32x4 a10 = {0.f,0.f,0.f,0.f}, a11 = {0.f,0.f,0.f,0.f};
  f32x4 a20 = {0.f,0.f,0.f,0.f}, a21 = {0.f,0.f,0.f,0.f};
  const short8 z8 = {0,0,0,0,0,0,0,0};

  // --- W11 fwd (s1,p2): 9 taps, K=32 in-ch; B-frags direct from x1t.
  //     Runs before the barrier: no LDS use, hides x0 ds_write drain. ---
  #pragma unroll
  for (int t = 0; t < 9; ++t) {
    const int ay = t / 3, ax = t % 3;
    const char* cb = ab2 + t * 4096 + lane * 16;
    short8 Ah0 = *(const short8*)(cb);
    short8 Al0 = *(const short8*)(cb + 1024);
    short8 Ah1 = *(const short8*)(cb + 2048);
    short8 Al1 = *(const short8*)(cb + 3072);
    int gy = iy + ay - 2;
    bool rowok = ((unsigned)gy < 128u);
    const char* rb = x1tb + ((size_t)(b * 128 + (rowok ? gy : 0))) * 8192 + q * 16;
    int c0 = (wv << 4) + nn + ax - 2;
    bool ok0 = rowok && ((unsigned)c0 < 128u);
    short8 B0 = *(const short8*)(rb + (size_t)(ok0 ? c0 : 0) * 64);
    if (!ok0) B0 = z8;
    int c1 = c0 + 64;
    bool ok1 = rowok && ((unsigned)c1 < 128u);
    short8 B1 = *(const short8*)(rb + (size_t)(ok1 ? c1 : 0) * 64);
    if (!ok1) B1 = z8;
    a00 = mfma16(Ah0, B0, a00); a00 = mfma16(Al0, B0, a00);
    a01 = mfma16(Ah1, B0, a01); a01 = mfma16(Al1, B0, a01);
    a10 = mfma16(Ah0, B1, a10); a10 = mfma16(Al0, B1, a10);
    a11 = mfma16(Ah1, B1, a11); a11 = mfma16(Al1, B1, a11);
    if (wv == 0) {
      int c2 = c0 + 128;
      bool ok2 = rowok && ((unsigned)c2 < 128u);
      short8 B2 = *(const short8*)(rb + (size_t)(ok2 ? c2 : 0) * 64);
      if (!ok2) B2 = z8;
      a20 = mfma16(Ah0, B2, a20); a20 = mfma16(Al0, B2, a20);
      a21 = mfma16(Ah1, B2, a21); a21 = mfma16(Al1, B2, a21);
    }
  }

  __syncthreads();   // x0s fully staged

  // --- W10 fwd (s2,p3): tap-pair chunks, k = qh*16 + ich ---
  #pragma unroll
  for (int c5 = 0; c5 < 5; ++c5) {
    const char* cb = ab2 + (36 + c5 * 4) * 1024 + lane * 16;
    short8 Ah0 = *(const short8*)(cb);
    short8 Al0 = *(const short8*)(cb + 1024);
    short8 Ah1 = *(const short8*)(cb + 2048);
    short8 Al1 = *(const short8*)(cb + 3072);
    int tl = 2 * c5 + qh; if (tl > 8) tl = 8;    // tap 9 zero-padded in A
    int by = tl / 3, bx = tl % 3;
    int p = bx & 1, hb = bx >> 1;
    const char* bb = (const char*)x0s + ((((ql * 3 + by) * 2 + p) * 146) + hb + nn) * 16 + wv * 256;
    short8 B0 = *(const short8*)(bb);
    short8 B1 = *(const short8*)(bb + 1024);
    a00 = mfma16(Ah0, B0, a00); a00 = mfma16(Al0, B0, a00);
    a01 = mfma16(Ah1, B0, a01); a01 = mfma16(Al1, B0, a01);
    a10 = mfma16(Ah0, B1, a10); a10 = mfma16(Al0, B1, a10);
    a11 = mfma16(Ah1, B1, a11); a11 = mfma16(Al1, B1, a11);
    if (wv == 0) {
      short8 B2 = *(const short8*)(bb + 2048);
      a20 = mfma16(Ah0, B2, a20); a20 = mfma16(Al0, B2, a20);
      a21 = mfma16(Ah1, B2, a21); a21 = mfma16(Al1, B2, a21);
    }
  }

  // --- store: Y1T[b][iy][ix][ch32] bf16, ix = f*16+nn, o = h*16+q*4+reg ---
  char* yp = ws + Y1T_OFF + (size_t)(b * 130 + iy) * Y1T_ROWB;
  auto st = [&](int f, f32x4 v0, f32x4 v1) {
    int ix = f * 16 + nn;
    if (ix < 130) {
      uint64_t lo = (uint64_t)packbf(v0[0], v0[1]) | ((uint64_t)packbf(v0[2], v0[3]) << 32);
      uint64_t hi = (uint64_t)packbf(v1[0], v1[1]) | ((uint64_t)packbf(v1[2], v1[3]) << 32);
      *(uint64_t*)(yp + ix * 64 + q * 8) = lo;
      *(uint64_t*)(yp + ix * 64 + 32 + q * 8) = hi;
    }
  };
  st(wv, a00, a01);
  st(wv + 4, a10, a11);
  if (wv == 0) st(8, a20, a21);
}

// ---------------------------------------------------------------------------
// outs_k: raw [0,8192) = out0 (per (b,jy,half), LDS-staged, 5 blk/CU);
//         raw [8192,10240) = out1 (per (b,jy), de-staged direct global).
__global__ __launch_bounds__(256, 5) void outs_k(const float* __restrict__ x0,
                                                 const float* __restrict__ b0,
                                                 const float* __restrict__ b1,
                                                 const float* __restrict__ gg,
                                                 const char* __restrict__ ws,
                                                 float* __restrict__ out) {
  // union LDS: out0 uses 21120 (x0s) + 8448 (y1s) = 29568 B; out1 uses none.
  __shared__ __align__(16) uint16_t smem[2 * 5 * 132 * 8 + 4 * 2 * 66 * 8];
  int raw = blockIdx.x, tid = threadIdx.x;
  int lane = tid & 63, wv = tid >> 6;
  int nn = lane & 15, q = lane >> 4;

  if (raw < 8192) {
    // ===================== out0 =====================
    uint16_t* x0s = smem;                       // [oct 2][row 5][col 132][ch 8]
    uint16_t* y1s = smem + 2 * 5 * 132 * 8;     // [q 4][ry 2][col 66][ch 8]
    int bid = xcd_swz(raw, 1024);
    int b = bid >> 9, jy = (bid >> 1) & 255;
    int jx_base = (bid & 1) << 7;

    { // stage x0: one 16B ch-octet granule per task
      const float* x0b = x0 + (size_t)b * 1048576;
      for (int e = tid; e < 1320; e += 256) {
        int c = e % 132, rr = e / 132, r = rr % 5, oct = rr / 5;
        int gy = jy + r - 2, gx = jx_base + c - 2;
        uint32_t w0 = 0u, w1 = 0u, w2 = 0u, w3 = 0u;
        if ((unsigned)gy < 256u && (unsigned)gx < 256u) {
          const float* p = x0b + (size_t)(oct * 8) * 65536 + gy * 256 + gx;
          w0 = packbf(p[0],      p[65536]);
          w1 = packbf(p[131072], p[196608]);
          w2 = packbf(p[262144], p[327680]);
          w3 = packbf(p[393216], p[458752]);
        }
        *(uint4*)((char*)x0s + (size_t)e * 16) = make_uint4(w0, w1, w2, w3);
      }
    }
    { // stage y1 rows uy+1, uy+2 (bf16 copy into q-planes)
      const char* y1tb = ws + Y1T_OFF;
      int uy = jy >> 1, c0 = jx_base >> 1;
      for (int e = tid; e < 528; e += 256) {
        int qq = e & 3, t = e >> 2, lc = t % 66, ry = t / 66;
        short8 v = *(const short8*)(y1tb +
            ((size_t)(b * 130 + uy + 1 + ry) * 132 + c0 + lc) * 64 + qq * 16);
        *(short8*)((char*)y1s + ((size_t)(qq * 2 + ry) * 66 + lc) * 16) = v;
      }
    }
    __syncthreads();

    int qh = q >> 1, ql = q & 1;
    const char* ab0 = ws + AB0_OFF;
    f32x4 acc[2];
    #pragma unroll
    for (int i = 0; i < 2; ++i) { acc[i][0]=0.f; acc[i][1]=0.f; acc[i][2]=0.f; acc[i][3]=0.f; }

    const uint16_t* xsl = x0s + ql * 5280;   // oct plane (5*132*8)
    const uint16_t* ysl = y1s + q * 1056;    // q plane (2*66*8)
    int pxb = wv * 32 + nn;

    // --- G00 5x5 (center zeroed), tap-pair chunks ---
    #pragma unroll
    for (int c = 0; c < 13; ++c) {
      short8 A = *(const short8*)(ab0 + c * 1024 + lane * 16);
      const int tA = 2 * c;
      const int tB = (2 * c + 1 > 24) ? 24 : 2 * c + 1;
      const int offA = ((tA / 5) * 132 + (tA % 5)) * 8;
      const int offB = ((tB / 5) * 132 + (tB % 5)) * 8;
      int toff = qh ? offB : offA;
      const uint16_t* base = xsl + toff + pxb * 8;
      short8 B0 = *(const short8*)(base);
      short8 B1 = *(const short8*)(base + 128);
      acc[0] = mfma16(A, B0, acc[0]);
      acc[1] = mfma16(A, B1, acc[1]);
    }

    // --- T10^T(Y1): compact cols + parity masks; rows fixed by jy parity ---
    {
      const short8 z8 = {0,0,0,0,0,0,0,0};
      if ((jy & 1) == 0) {
        #pragma unroll
        for (int bx = 0; bx < 3; ++bx) {
          short8 A = *(const short8*)(ab0 + (16 + bx) * 1024 + lane * 16);
          bool keep = (((nn + 3 - bx) & 1) == 0);
          int cb = (nn + 3 - bx) >> 1;
          const uint16_t* base = ysl + (cb + wv * 16) * 8;   // ry = 0
          short8 B0 = *(const short8*)(base);
          short8 B1 = *(const short8*)(base + 64);
          if (!keep) { B0 = z8; B1 = z8; }
          acc[0] = mfma16(A, B0, acc[0]);
          acc[1] = mfma16(A, B1, acc[1]);
        }
      } else {
        #pragma unroll
        for (int s = 0; s < 2; ++s) {          // s=0: by=0 (ry=1); s=1: by=2 (ry=0)
          const int chunkb = s ? 19 : 13;
          const int rybase = s ? 0 : 1;
          #pragma unroll
          for (int bx = 0; bx < 3; ++bx) {
            short8 A = *(const short8*)(ab0 + (chunkb + bx) * 1024 + lane * 16);
            bool keep = (((nn + 3 - bx) & 1) == 0);
            int cb = (nn + 3 - bx) >> 1;
            const uint16_t* base = ysl + (rybase * 66 + cb + wv * 16) * 8;
            short8 B0 = *(const short8*)(base);
            short8 B1 = *(const short8*)(base + 64);
            if (!keep) { B0 = z8; B1 = z8; }
            acc[0] = mfma16(A, B0, acc[0]);
            acc[1] = mfma16(A, B1, acc[1]);
          }
        }
      }
    }

    // --- hollow center: -G10c[jy-parity][px-parity], column-parity masked ---
    {
      const short8 z8 = {0,0,0,0,0,0,0,0};
      short8 A = *(const short8*)(ab0 + (22 + (jy & 1)) * 1024 + lane * 16);
      const uint16_t* base = xsl + (2 * 132 + 2) * 8 + pxb * 8;
      short8 B0 = *(const short8*)(base);
      short8 B1 = *(const short8*)(base + 128);
      bool keep = ((nn & 1) == qh);   // k<16 rows multiply even px, k>=16 odd px
      if (!keep) { B0 = z8; B1 = z8; }
      acc[0] = mfma16(A, B0, acc[0]);
      acc[1] = mfma16(A, B1, acc[1]);
    }

    // --- epilogue: out = b0_hat*g0 - acc ---
    float rs0 = gg[0] / sqrtf(((const float*)(ws + SUM_OFF))[0]);
    #pragma unroll
    for (int i = 0; i < 2; ++i) {
      int px = jx_base + wv * 32 + i * 16 + nn;
      #pragma unroll
      for (int reg = 0; reg < 4; ++reg) {
        int m = q * 4 + reg;
        size_t boff = ((size_t)m * 256 + jy) * 256 + px;
        out[((size_t)(b * 16 + m) * 256 + jy) * 256 + px] = b0[boff] * rs0 - acc[i][reg];
      }
    }
    return;
  }

  // ===================== out1 (de-staged) =====================
  {
    int bid = xcd_swz(raw - 8192, 256);
    int b = bid >> 7, jy = bid & 127;
    const char* ab1 = ws + AB1_OFF;
    // Y1T/X1T are in exact B-frag order: [.][row][col][ch32], 64 B per col,
    // quad q at +q*16.  Per-block footprint (3 y1 rows + 1 x1 row ~ 33 KB)
    // is L1/L2-resident -> direct global reads, no LDS, no barrier.
    const char* yb = ws + Y1T_OFF + ((size_t)(b * 130 + jy) * 132) * 64 + q * 16;
    const char* xb = ws + X1T_OFF + ((size_t)(b * 128 + jy) * 128) * 64 + q * 16;
    f32x4 acc[2][2];
    #pragma unroll
    for (int i = 0; i < 2; ++i)
      #pragma unroll
      for (int h = 0; h < 2; ++h) { acc[i][h][0]=0.f; acc[i][h][1]=0.f; acc[i][h][2]=0.f; acc[i][h][3]=0.f; }

    int pxb = wv * 32 + nn;

    #pragma unroll
    for (int t = 0; t < 9; ++t) {
      const int ay = t / 3, ax = t % 3;
      short8 A0 = *(const short8*)(ab1 + (t * 2 + 0) * 1024 + lane * 16);
      short8 A1 = *(const short8*)(ab1 + (t * 2 + 1) * 1024 + lane * 16);
      const char* base = yb + (size_t)((2 - ay) * 132 + (2 - ax) + pxb) * 64;
      short8 B0 = *(const short8*)(base);
      short8 B1 = *(const short8*)(base + 1024);   // +16 cols
      acc[0][0] = mfma16(A0, B0, acc[0][0]);
      acc[0][1] = mfma16(A1, B0, acc[0][1]);
      acc[1][0] = mfma16(A0, B1, acc[1][0]);
      acc[1][1] = mfma16(A1, B1, acc[1][1]);
    }
    { // -sub1 blockdiag * x1
      short8 A0 = *(const short8*)(ab1 + 18 * 1024 + lane * 16);
      short8 A1 = *(const short8*)(ab1 + 19 * 1024 + lane * 16);
      const char* base = xb + (size_t)pxb * 64;
      short8 B0 = *(const short8*)(base);
      short8 B1 = *(const short8*)(base + 1024);
      acc[0][0] = mfma16(A0, B0, acc[0][0]);
      acc[0][1] = mfma16(A1, B0, acc[0][1]);
      acc[1][0] = mfma16(A0, B1, acc[1][0]);
      acc[1][1] = mfma16(A1, B1, acc[1][1]);
    }

    float rs1 = gg[1] / sqrtf(((const float*)(ws + SUM_OFF))[1]);
    #pragma unroll
    for (int i = 0; i < 2; ++i) {
      int px = wv * 32 + i * 16 + nn;
      #pragma unroll
      for (int h = 0; h < 2; ++h)
        #pragma unroll
        for (int reg = 0; reg < 4; ++reg) {
          int m = h * 16 + q * 4 + reg;
          size_t boff = ((size_t)m * 128 + jy) * 128 + px;
          out[16777216 + ((size_t)(b * 32 + m) * 128 + jy) * 128 + px] = b1[boff] * rs1 - acc[i][h][reg];
        }
    }
  }
}

// ---------------------------------------------------------------------------
extern "C" void kernel_launch(void* const* d_in, const int* in_sizes, int n_in,
                              void* d_out, int out_size, void* d_ws, size_t ws_size,
                              hipStream_t stream) {
  const float* x0  = (const float*)d_in[0];
  const float* x1  = (const float*)d_in[1];
  const float* W00 = (const float*)d_in[2];
  const float* W10 = (const float*)d_in[3];
  const float* W11 = (const float*)d_in[4];
  const float* b0  = (const float*)d_in[5];
  const float* b1  = (const float*)d_in[6];
  const float* g   = (const float*)d_in[7];
  float* out = (float*)d_out;
  char* ws   = (char*)d_ws;

  prep_k<<<2344, 256, 0, stream>>>(x1, W00, W10, W11, b0, b1, ws);
  y1m_k<<<2088, 256, 0, stream>>>(x0, ws);
  outs_k<<<10240, 256, 0, stream>>>(x0, b0, b1, g, ws, out);
}